// Round 1
// baseline (2782.085 us; speedup 1.0000x reference)
//
#include <hip/hip_runtime.h>
#include <hip/hip_fp16.h>

#define B_   16
#define L_   4096
#define DIN  64
#define H_   256
#define N_   32
#define NL_  4
#define DOUT 10
#define CH_  32          // chunks per sequence
#define T_   128         // L_/CH_

typedef _Float16 half8 __attribute__((ext_vector_type(8)));
typedef float f32x4 __attribute__((ext_vector_type(4)));

// ---------------- parameter precompute: w = exp(dt*A), C~ = 2*C*expm1(dtA)/A, wT = w^T ----------------
__global__ __launch_bounds__(256) void params_k(
    const float* __restrict__ log_dt, const float* __restrict__ log_A_real,
    const float* __restrict__ A_imag, const float* __restrict__ C_re, const float* __restrict__ C_im,
    float* __restrict__ wre, float* __restrict__ wim,
    float* __restrict__ ctr, float* __restrict__ cti,
    float* __restrict__ wtr, float* __restrict__ wti)
{
    int idx = blockIdx.x * 256 + threadIdx.x;      // [0, NL*H*N)
    int ih  = idx >> 5;                            // i*H + h
    float dt  = expf(log_dt[ih]);
    float Are = -expf(log_A_real[idx]);
    float Aim = A_imag[idx];
    float xr = dt * Are, xi = dt * Aim;
    float ex = expf(xr);
    float cy = cosf(xi), sy = sinf(xi);
    float wr = ex * cy, wi_ = ex * sy;
    // expm1(xr + i*xi): Re = expm1(xr)*cos(xi) - 2*sin^2(xi/2), Im = ex*sin(xi)
    float sh = sinf(0.5f * xi);
    float em_re = expm1f(xr) * cy - 2.f * sh * sh;
    float em_im = wi_;
    float inv = 1.f / (Are * Are + Aim * Aim);
    float qr = (em_re * Are + em_im * Aim) * inv;
    float qi = (em_im * Are - em_re * Aim) * inv;
    float crv = C_re[idx], civ = C_im[idx];
    wre[idx] = wr;  wim[idx] = wi_;
    ctr[idx] = 2.f * (crv * qr - civ * qi);        // fold factor 2 in
    cti[idx] = 2.f * (crv * qi + civ * qr);
    float txr = (float)T_ * xr, txi = (float)T_ * xi;
    float exT = expf(txr);
    wtr[idx] = exT * cosf(txi);
    wti[idx] = exT * sinf(txi);
}

__global__ __launch_bounds__(256) void wconv_k(const float* __restrict__ w, _Float16* __restrict__ w16)
{
    int idx = blockIdx.x * 256 + threadIdx.x;
    w16[idx] = (_Float16)w[idx];
}

// ---------------- encoder: h[b,hh,l] = sum_i x[b,l,i]*ew[hh,i] + eb[hh] ----------------
__global__ __launch_bounds__(256) void encoder_k(
    const float* __restrict__ x, const float* __restrict__ ew,
    const float* __restrict__ eb, float* __restrict__ hbuf)
{
    __shared__ float xt[64][64];
    int blk = blockIdx.x;
    int b  = blk >> 6;
    int l0 = (blk & 63) << 6;
    int t  = threadIdx.x;
    {
        int r = t >> 2, cp = (t & 3) * 16;
        const float4* src = (const float4*)(x + ((size_t)(b * L_ + l0 + r)) * DIN + cp);
        float4* dst = (float4*)&xt[r][cp];
#pragma unroll
        for (int j = 0; j < 4; j++) dst[j] = src[j];
    }
    float wrg[64];
#pragma unroll
    for (int i = 0; i < 64; i += 4) {
        float4 wv = *(const float4*)(ew + t * 64 + i);
        wrg[i] = wv.x; wrg[i+1] = wv.y; wrg[i+2] = wv.z; wrg[i+3] = wv.w;
    }
    float bias = eb[t];
    __syncthreads();
    float* out = hbuf + ((size_t)(b * H_ + t)) * L_ + l0;
    for (int l = 0; l < 64; l += 4) {
        float4 res;
        float* rp = (float*)&res;
#pragma unroll
        for (int q = 0; q < 4; q++) {
            float a0 = 0.f, a1 = 0.f;
#pragma unroll
            for (int i = 0; i < 64; i += 2) {
                a0 = fmaf(xt[l+q][i],   wrg[i],   a0);
                a1 = fmaf(xt[l+q][i+1], wrg[i+1], a1);
            }
            rp[q] = a0 + a1 + bias;
        }
        *(float4*)(out + l) = res;
    }
}

// ---------------- phase 1: per-chunk local final states (zero init) ----------------
__global__ __launch_bounds__(256) void phase1_k(
    const float* __restrict__ hbuf, const float* __restrict__ wre, const float* __restrict__ wim,
    float* __restrict__ F)
{
    int tid = blockIdx.x * 256 + threadIdx.x;      // b*H*CH + h*CH + c
    int c  = tid & (CH_ - 1);
    int bh = tid >> 5;
    int hh = bh & (H_ - 1);
    float wr[N_], wi[N_], Sr[N_], Si[N_];
#pragma unroll
    for (int n = 0; n < N_; n++) {
        wr[n] = wre[hh * N_ + n]; wi[n] = wim[hh * N_ + n];
        Sr[n] = 0.f; Si[n] = 0.f;
    }
    const float* z = hbuf + (size_t)bh * L_ + c * T_;
    for (int tt = 0; tt < T_; tt += 4) {
        float4 zv = *(const float4*)(z + tt);
        float za[4] = {zv.x, zv.y, zv.z, zv.w};
#pragma unroll
        for (int q = 0; q < 4; q++) {
            float zz = za[q];
#pragma unroll
            for (int n = 0; n < N_; n++) {
                float nr = fmaf(wr[n], Sr[n], zz);
                nr = fmaf(-wi[n], Si[n], nr);
                float ni = wr[n] * Si[n];
                ni = fmaf(wi[n], Sr[n], ni);
                Sr[n] = nr; Si[n] = ni;
            }
        }
    }
    float* Ft = F + (size_t)tid * 64;
#pragma unroll
    for (int n = 0; n < N_; n++) {
        float2 fv; fv.x = Sr[n]; fv.y = Si[n];
        *(float2*)(Ft + 2 * n) = fv;
    }
}

// ---------------- phase 2: sequential prefix over chunks; F overwritten with chunk-initial states ----------------
__global__ __launch_bounds__(256) void phase2_k(
    float* __restrict__ F, const float* __restrict__ wtr, const float* __restrict__ wti)
{
    int tid = blockIdx.x * 256 + threadIdx.x;      // b*H*N + h*N + n
    int n  = tid & (N_ - 1);
    int bh = tid >> 5;
    int hh = bh & (H_ - 1);
    float wr = wtr[hh * N_ + n], wi = wti[hh * N_ + n];
    float cr = 0.f, ci = 0.f;
    float* base = F + (size_t)bh * CH_ * 64 + 2 * n;
#pragma unroll 4
    for (int c = 0; c < CH_; c++) {
        float fr = base[c * 64], fi = base[c * 64 + 1];
        base[c * 64] = cr; base[c * 64 + 1] = ci;   // initial state for this chunk
        float nr = fmaf(wr, cr, fr);
        nr = fmaf(-wi, ci, nr);
        float ni = fmaf(wi, cr, fi);
        ni = fmaf(wr, ci, ni);
        cr = nr; ci = ni;
    }
}

// ---------------- phase 3: recurrence with carried state + output + D-skip + gelu -> f16 ----------------
__global__ __launch_bounds__(256) void phase3_k(
    const float* __restrict__ hbuf, const float* __restrict__ wre, const float* __restrict__ wim,
    const float* __restrict__ ctr, const float* __restrict__ cti,
    const float* __restrict__ F, const float* __restrict__ Dl, _Float16* __restrict__ y16)
{
    int tid = blockIdx.x * 256 + threadIdx.x;
    int c  = tid & (CH_ - 1);
    int bh = tid >> 5;
    int hh = bh & (H_ - 1);
    float wr[N_], wi[N_], cr[N_], ci[N_], Sr[N_], Si[N_];
    const float* Ft = F + (size_t)tid * 64;
#pragma unroll
    for (int n = 0; n < N_; n++) {
        wr[n] = wre[hh * N_ + n]; wi[n] = wim[hh * N_ + n];
        cr[n] = ctr[hh * N_ + n]; ci[n] = cti[hh * N_ + n];
        Sr[n] = Ft[2 * n]; Si[n] = Ft[2 * n + 1];
    }
    float Dh = Dl[hh];
    const float* z = hbuf + (size_t)bh * L_ + c * T_;
    _Float16* yo  = y16 + (size_t)bh * L_ + c * T_;
    for (int tt = 0; tt < T_; tt += 4) {
        float4 zv = *(const float4*)(z + tt);
        float za[4] = {zv.x, zv.y, zv.z, zv.w};
        union { uint2 u2; _Float16 hf[4]; } ov;
#pragma unroll
        for (int q = 0; q < 4; q++) {
            float zz = za[q];
            float a0 = 0.f, a1 = 0.f, a2 = 0.f, a3 = 0.f;
#pragma unroll
            for (int n = 0; n < N_; n++) {
                float nr = fmaf(wr[n], Sr[n], zz);
                nr = fmaf(-wi[n], Si[n], nr);
                float ni = wr[n] * Si[n];
                ni = fmaf(wi[n], Sr[n], ni);
                Sr[n] = nr; Si[n] = ni;
                if ((n & 3) == 0)      { a0 = fmaf(cr[n], nr, a0); a0 = fmaf(-ci[n], ni, a0); }
                else if ((n & 3) == 1) { a1 = fmaf(cr[n], nr, a1); a1 = fmaf(-ci[n], ni, a1); }
                else if ((n & 3) == 2) { a2 = fmaf(cr[n], nr, a2); a2 = fmaf(-ci[n], ni, a2); }
                else                   { a3 = fmaf(cr[n], nr, a3); a3 = fmaf(-ci[n], ni, a3); }
            }
            float v = (a0 + a1) + (a2 + a3);
            v = fmaf(Dh, zz, v);
            // gelu, tanh approximation (matches jax.nn.gelu approximate=True)
            float t3  = v * v * v;
            float arg = 0.7978845608028654f * fmaf(0.044715f, t3, v);
            float e   = __expf(2.f * arg);
            float th  = 1.f - 2.f / (e + 1.f);
            float gl  = 0.5f * v * (1.f + th);
            ov.hf[q] = (_Float16)gl;
        }
        *(uint2*)(yo + tt) = ov.u2;
    }
}

// ---------------- GLU GEMM: g = W(512x256) @ y(256 x 32-lane tile), fused bias/GLU/residual/LN ----------------
__global__ __launch_bounds__(256) void glu_k(
    const _Float16* __restrict__ W, const _Float16* __restrict__ y16,
    const float* __restrict__ outb, const float* __restrict__ lnw,
    const float* __restrict__ lnb, float* __restrict__ hbuf)
{
    __shared__ float smem[512 * 33];              // 67584 B; union: yT(f16 [32][264]) during K-loop, g after
    __shared__ float red[2][8][32];
    __shared__ float mus[32], rss[32];
    _Float16* yT = (_Float16*)smem;
    float* g = smem;
    int b  = blockIdx.y;
    int l0 = blockIdx.x << 5;
    int t  = threadIdx.x;
    int lane = t & 63, wid = t >> 6;
    int l15 = lane & 15, quad = lane >> 4;
    // stage yT[l][k] = y16[b, k, l0+l]  (transposed so B-frag reads are contiguous in k)
    {
        int k = t;
        const uint4* src = (const uint4*)(y16 + ((size_t)(b * H_ + k)) * L_ + l0);
        uint4 v[4];
#pragma unroll
        for (int j = 0; j < 4; j++) v[j] = src[j];
        const _Float16* hv = (const _Float16*)v;
#pragma unroll
        for (int j = 0; j < 32; j++) yT[j * 264 + k] = hv[j];
    }
    __syncthreads();
    f32x4 acc[8][2];
#pragma unroll
    for (int mt = 0; mt < 8; mt++) {
        acc[mt][0] = (f32x4){0.f, 0.f, 0.f, 0.f};
        acc[mt][1] = (f32x4){0.f, 0.f, 0.f, 0.f};
    }
#pragma unroll
    for (int ks = 0; ks < 8; ks++) {
        int kk = ks * 32 + quad * 8;
        half8 b0 = *(const half8*)&yT[l15 * 264 + kk];
        half8 b1 = *(const half8*)&yT[(16 + l15) * 264 + kk];
#pragma unroll
        for (int mt = 0; mt < 8; mt++) {
            half8 a = *(const half8*)(W + ((size_t)(wid * 128 + mt * 16 + l15)) * H_ + kk);
            acc[mt][0] = __builtin_amdgcn_mfma_f32_16x16x32_f16(a, b0, acc[mt][0], 0, 0, 0);
            acc[mt][1] = __builtin_amdgcn_mfma_f32_16x16x32_f16(a, b1, acc[mt][1], 0, 0, 0);
        }
    }
    __syncthreads();                               // yT dead; reuse smem as g
#pragma unroll
    for (int mt = 0; mt < 8; mt++)
#pragma unroll
        for (int nt = 0; nt < 2; nt++)
#pragma unroll
            for (int r = 0; r < 4; r++)
                g[(wid * 128 + mt * 16 + quad * 4 + r) * 33 + nt * 16 + l15] = acc[mt][nt][r];
    __syncthreads();
    int l = t & 31, c0 = t >> 5;
    float u[32], s1 = 0.f, s2 = 0.f;
#pragma unroll
    for (int j = 0; j < 32; j++) {
        int ch = c0 + 8 * j;
        float g1 = g[ch * 33 + l] + outb[ch];
        float g2 = g[(ch + 256) * 33 + l] + outb[ch + 256];
        float sg = 1.f / (1.f + __expf(-g2));
        float uu = g1 * sg + hbuf[((size_t)(b * H_ + ch)) * L_ + l0 + l];  // GLU + residual
        u[j] = uu; s1 += uu; s2 = fmaf(uu, uu, s2);
    }
    red[0][c0][l] = s1; red[1][c0][l] = s2;
    __syncthreads();
    if (t < 32) {
        float a = 0.f, q = 0.f;
#pragma unroll
        for (int p = 0; p < 8; p++) { a += red[0][p][t]; q += red[1][p][t]; }
        float mu  = a * (1.f / 256.f);
        float var = q * (1.f / 256.f) - mu * mu;
        mus[t] = mu; rss[t] = rsqrtf(var + 1e-5f);
    }
    __syncthreads();
    float mu = mus[l], rs = rss[l];
#pragma unroll
    for (int j = 0; j < 32; j++) {
        int ch = c0 + 8 * j;
        hbuf[((size_t)(b * H_ + ch)) * L_ + l0 + l] = (u[j] - mu) * rs * lnw[ch] + lnb[ch];
    }
}

// ---------------- decoder: out[b,l,o] = sum_h h[b,h,l]*dw[o,h] + db[o] ----------------
__global__ __launch_bounds__(256) void decoder_k(
    const float* __restrict__ hbuf, const float* __restrict__ dw,
    const float* __restrict__ db, float* __restrict__ out)
{
    __shared__ float ht[256][64];
    __shared__ float wt[DOUT * H_];
    int blk = blockIdx.x;
    int b  = blk >> 6;
    int l0 = (blk & 63) << 6;
    int t  = threadIdx.x;
    {
        const float4* src = (const float4*)(hbuf + ((size_t)(b * H_ + t)) * L_ + l0);
        float4* dst = (float4*)&ht[t][0];
#pragma unroll
        for (int j = 0; j < 16; j++) dst[j] = src[j];
    }
    for (int idx = t; idx < DOUT * H_; idx += 256) wt[idx] = dw[idx];
    __syncthreads();
    int l = t & 63, og = t >> 6;
    for (int o = og; o < DOUT; o += 4) {
        float a0 = 0.f, a1 = 0.f;
#pragma unroll 8
        for (int k = 0; k < H_; k += 2) {
            a0 = fmaf(ht[k][l],     wt[o * H_ + k],     a0);
            a1 = fmaf(ht[k + 1][l], wt[o * H_ + k + 1], a1);
        }
        out[((size_t)(b * L_ + l0 + l)) * DOUT + o] = a0 + a1 + db[o];
    }
}

extern "C" void kernel_launch(void* const* d_in, const int* in_sizes, int n_in,
                              void* d_out, int out_size, void* d_ws, size_t ws_size,
                              hipStream_t stream)
{
    (void)in_sizes; (void)n_in; (void)out_size; (void)ws_size;
    const float* x          = (const float*)d_in[0];
    const float* enc_w      = (const float*)d_in[1];
    const float* enc_b      = (const float*)d_in[2];
    const float* log_dt     = (const float*)d_in[3];
    const float* log_A_real = (const float*)d_in[4];
    const float* A_imag     = (const float*)d_in[5];
    const float* C_re       = (const float*)d_in[6];
    const float* C_im       = (const float*)d_in[7];
    const float* Dp         = (const float*)d_in[8];
    const float* out_w      = (const float*)d_in[9];
    const float* out_b      = (const float*)d_in[10];
    const float* ln_w       = (const float*)d_in[11];
    const float* ln_b       = (const float*)d_in[12];
    const float* dec_w      = (const float*)d_in[13];
    const float* dec_b      = (const float*)d_in[14];
    float* outp = (float*)d_out;

    // workspace carve-up (~136 MB)
    char* ws = (char*)d_ws;
    float* hbuf = (float*)ws;      ws += (size_t)B_ * H_ * L_ * 4;        // 64 MB
    _Float16* y16 = (_Float16*)ws; ws += (size_t)B_ * H_ * L_ * 2;        // 32 MB
    float* F = (float*)ws;         ws += (size_t)B_ * H_ * CH_ * N_ * 2 * 4;  // 32 MB
    size_t tb = (size_t)NL_ * H_ * N_;
    float* wre = (float*)ws; ws += tb * 4;
    float* wim = (float*)ws; ws += tb * 4;
    float* ctr = (float*)ws; ws += tb * 4;
    float* cti = (float*)ws; ws += tb * 4;
    float* wtr = (float*)ws; ws += tb * 4;
    float* wti = (float*)ws; ws += tb * 4;
    _Float16* W16 = (_Float16*)ws; ws += (size_t)NL_ * 2 * H_ * H_ * 2;   // 1 MB

    params_k<<<(int)(tb / 256), 256, 0, stream>>>(log_dt, log_A_real, A_imag, C_re, C_im,
                                                  wre, wim, ctr, cti, wtr, wti);
    wconv_k<<<(NL_ * 2 * H_ * H_) / 256, 256, 0, stream>>>(out_w, W16);
    encoder_k<<<B_ * (L_ / 64), 256, 0, stream>>>(x, enc_w, enc_b, hbuf);
    for (int i = 0; i < NL_; i++) {
        size_t o = (size_t)i * H_ * N_;
        phase1_k<<<(B_ * H_ * CH_) / 256, 256, 0, stream>>>(hbuf, wre + o, wim + o, F);
        phase2_k<<<(B_ * H_ * N_) / 256, 256, 0, stream>>>(F, wtr + o, wti + o);
        phase3_k<<<(B_ * H_ * CH_) / 256, 256, 0, stream>>>(hbuf, wre + o, wim + o, ctr + o, cti + o,
                                                            F, Dp + i * H_, y16);
        glu_k<<<dim3(L_ / 32, B_), 256, 0, stream>>>(W16 + (size_t)i * 2 * H_ * H_, y16,
                                                     out_b + i * 2 * H_, ln_w + i * H_, ln_b + i * H_, hbuf);
    }
    decoder_k<<<B_ * (L_ / 64), 256, 0, stream>>>(hbuf, dec_w, dec_b, outp);
}

// Round 2
// 1250.005 us; speedup vs baseline: 2.2257x; 2.2257x over previous
//
#include <hip/hip_runtime.h>
#include <hip/hip_fp16.h>

#define B_   16
#define L_   4096
#define DIN  64
#define H_   256
#define N_   32
#define NL_  4
#define DOUT 10
#define CH_  32          // chunks per sequence
#define T_   128         // L_/CH_
#define NH_  16          // states per lane (pair-split)

// Layout note: hbuf and y16 rows use the chunk-transposed ("permuted") order:
//   actual l = c*T_ + tt  <->  stored p = tt*CH_ + c
// glu_k is pointwise in l, so it operates on p directly with no change.

typedef _Float16 half8 __attribute__((ext_vector_type(8)));
typedef float f32x4 __attribute__((ext_vector_type(4)));

// ---------------- parameter precompute: w = exp(dt*A), C~ = 2*C*expm1(dtA)/A, wT = w^T ----------------
__global__ __launch_bounds__(256) void params_k(
    const float* __restrict__ log_dt, const float* __restrict__ log_A_real,
    const float* __restrict__ A_imag, const float* __restrict__ C_re, const float* __restrict__ C_im,
    float* __restrict__ wre, float* __restrict__ wim,
    float* __restrict__ ctr, float* __restrict__ cti,
    float* __restrict__ wtr, float* __restrict__ wti)
{
    int idx = blockIdx.x * 256 + threadIdx.x;      // [0, NL*H*N)
    int ih  = idx >> 5;                            // i*H + h
    float dt  = expf(log_dt[ih]);
    float Are = -expf(log_A_real[idx]);
    float Aim = A_imag[idx];
    float xr = dt * Are, xi = dt * Aim;
    float ex = expf(xr);
    float cy = cosf(xi), sy = sinf(xi);
    float wr = ex * cy, wi_ = ex * sy;
    float sh = sinf(0.5f * xi);
    float em_re = expm1f(xr) * cy - 2.f * sh * sh;
    float em_im = wi_;
    float inv = 1.f / (Are * Are + Aim * Aim);
    float qr = (em_re * Are + em_im * Aim) * inv;
    float qi = (em_im * Are - em_re * Aim) * inv;
    float crv = C_re[idx], civ = C_im[idx];
    wre[idx] = wr;  wim[idx] = wi_;
    ctr[idx] = 2.f * (crv * qr - civ * qi);
    cti[idx] = 2.f * (crv * qi + civ * qr);
    float txr = (float)T_ * xr, txi = (float)T_ * xi;
    float exT = expf(txr);
    wtr[idx] = exT * cosf(txi);
    wti[idx] = exT * sinf(txi);
}

__global__ __launch_bounds__(256) void wconv_k(const float* __restrict__ w, _Float16* __restrict__ w16)
{
    int idx = blockIdx.x * 256 + threadIdx.x;
    w16[idx] = (_Float16)w[idx];
}

// ---------------- encoder: h[b,hh,p] = sum_i x[b,l(p),i]*ew[hh,i] + eb[hh]  (permuted write) ----------------
__global__ __launch_bounds__(256) void encoder_k(
    const float* __restrict__ x, const float* __restrict__ ew,
    const float* __restrict__ eb, float* __restrict__ hbuf)
{
    __shared__ float xt[64][68];                   // row j <-> p = g*64 + j ; padded
    int blk = blockIdx.x;
    int b  = blk >> 6;
    int g  = blk & 63;                             // p-block: tt in {2g, 2g+1}, all c
    int t  = threadIdx.x;
    {
        int c = t >> 3, piece = t & 7;             // 8 threads load 128 consecutive floats (2 x-rows)
        const float4* src = (const float4*)(x + ((size_t)(b * L_ + c * T_ + 2 * g)) * DIN + piece * 16);
#pragma unroll
        for (int j = 0; j < 4; j++) {
            float4 v = src[j];
            int f = piece * 16 + j * 4;            // [0,128)
            int r = f >> 6, i = f & 63;            // r = tt-2g, i = din idx
            *(float4*)&xt[r * 32 + c][i] = v;
        }
    }
    float wrg[64];
#pragma unroll
    for (int i = 0; i < 64; i += 4) {
        float4 wv = *(const float4*)(ew + t * 64 + i);
        wrg[i] = wv.x; wrg[i+1] = wv.y; wrg[i+2] = wv.z; wrg[i+3] = wv.w;
    }
    float bias = eb[t];
    __syncthreads();
    float* out = hbuf + ((size_t)(b * H_ + t)) * L_ + g * 64;
    for (int j0 = 0; j0 < 64; j0 += 4) {
        float4 res;
        float* rp = (float*)&res;
#pragma unroll
        for (int q = 0; q < 4; q++) {
            float a0 = 0.f, a1 = 0.f;
#pragma unroll
            for (int i = 0; i < 64; i += 2) {
                a0 = fmaf(xt[j0+q][i],   wrg[i],   a0);
                a1 = fmaf(xt[j0+q][i+1], wrg[i+1], a1);
            }
            rp[q] = a0 + a1 + bias;
        }
        *(float4*)(out + j0) = res;
    }
}

// ---------------- phase 1: per-chunk local final states; 2 lanes per (b,h,c), 16 states each ----------------
__global__ __launch_bounds__(256, 4) void phase1_k(
    const float* __restrict__ hbuf, const float* __restrict__ wre, const float* __restrict__ wim,
    float* __restrict__ F)
{
    int g  = blockIdx.x * 256 + threadIdx.x;       // [0, B*H*CH*2)
    int s  = g & 1;
    int c  = (g >> 1) & (CH_ - 1);
    int bh = g >> 6;
    int hh = bh & (H_ - 1);
    float wr[NH_], wi[NH_], Sr[NH_], Si[NH_];
    int pb = hh * N_ + s * NH_;
#pragma unroll
    for (int k = 0; k < NH_; k++) {
        wr[k] = wre[pb + k]; wi[k] = wim[pb + k];
        Sr[k] = 0.f; Si[k] = 0.f;
    }
    const float* z = hbuf + (size_t)bh * L_;
    for (int tt = 0; tt < T_; tt += 4) {
        float za[4];
#pragma unroll
        for (int q = 0; q < 4; q++) za[q] = z[(tt + q) * CH_ + c];
#pragma unroll
        for (int q = 0; q < 4; q++) {
            float zz = za[q];
#pragma unroll
            for (int k = 0; k < NH_; k++) {
                float nr = fmaf(wr[k], Sr[k], zz);
                nr = fmaf(-wi[k], Si[k], nr);
                float ni = wr[k] * Si[k];
                ni = fmaf(wi[k], Sr[k], ni);
                Sr[k] = nr; Si[k] = ni;
            }
        }
    }
    float* Ft = F + ((size_t)bh * CH_ + c) * 64 + s * 2 * NH_;
#pragma unroll
    for (int k = 0; k < NH_; k++) {
        float2 fv; fv.x = Sr[k]; fv.y = Si[k];
        *(float2*)(Ft + 2 * k) = fv;
    }
}

// ---------------- phase 2: sequential prefix over chunks; F overwritten with chunk-initial states ----------------
__global__ __launch_bounds__(256) void phase2_k(
    float* __restrict__ F, const float* __restrict__ wtr, const float* __restrict__ wti)
{
    int tid = blockIdx.x * 256 + threadIdx.x;      // b*H*N + h*N + n
    int n  = tid & (N_ - 1);
    int bh = tid >> 5;
    int hh = bh & (H_ - 1);
    float wr = wtr[hh * N_ + n], wi = wti[hh * N_ + n];
    float cr = 0.f, ci = 0.f;
    float* base = F + (size_t)bh * CH_ * 64 + 2 * n;
#pragma unroll 4
    for (int c = 0; c < CH_; c++) {
        float fr = base[c * 64], fi = base[c * 64 + 1];
        base[c * 64] = cr; base[c * 64 + 1] = ci;
        float nr = fmaf(wr, cr, fr);
        nr = fmaf(-wi, ci, nr);
        float ni = fmaf(wi, cr, fi);
        ni = fmaf(wr, ci, ni);
        cr = nr; ci = ni;
    }
}

// ---------------- phase 3: recurrence + output + D-skip + gelu -> f16 (pair-split, permuted) ----------------
__global__ __launch_bounds__(256, 4) void phase3_k(
    const float* __restrict__ hbuf, const float* __restrict__ wre, const float* __restrict__ wim,
    const float* __restrict__ ctr, const float* __restrict__ cti,
    const float* __restrict__ F, const float* __restrict__ Dl, _Float16* __restrict__ y16)
{
    int g  = blockIdx.x * 256 + threadIdx.x;
    int s  = g & 1;
    int c  = (g >> 1) & (CH_ - 1);
    int bh = g >> 6;
    int hh = bh & (H_ - 1);
    float wr[NH_], wi[NH_], cr[NH_], ci[NH_], Sr[NH_], Si[NH_];
    int pb = hh * N_ + s * NH_;
    const float* Ft = F + ((size_t)bh * CH_ + c) * 64 + s * 2 * NH_;
#pragma unroll
    for (int k = 0; k < NH_; k++) {
        wr[k] = wre[pb + k]; wi[k] = wim[pb + k];
        cr[k] = ctr[pb + k]; ci[k] = cti[pb + k];
        Sr[k] = Ft[2 * k]; Si[k] = Ft[2 * k + 1];
    }
    float Dh = Dl[hh];
    const float* z = hbuf + (size_t)bh * L_;
    _Float16* yo  = y16 + (size_t)bh * L_;
    for (int tt = 0; tt < T_; tt += 4) {
        float za[4];
#pragma unroll
        for (int q = 0; q < 4; q++) za[q] = z[(tt + q) * CH_ + c];
        _Float16 gls[4];
#pragma unroll
        for (int q = 0; q < 4; q++) {
            float zz = za[q];
            float a0 = 0.f, a1 = 0.f;
#pragma unroll
            for (int k = 0; k < NH_; k++) {
                float nr = fmaf(wr[k], Sr[k], zz);
                nr = fmaf(-wi[k], Si[k], nr);
                float ni = wr[k] * Si[k];
                ni = fmaf(wi[k], Sr[k], ni);
                Sr[k] = nr; Si[k] = ni;
                if (k & 1) { a1 = fmaf(cr[k], nr, a1); a1 = fmaf(-ci[k], ni, a1); }
                else       { a0 = fmaf(cr[k], nr, a0); a0 = fmaf(-ci[k], ni, a0); }
            }
            float part = a0 + a1;
            float v = part + __shfl_xor(part, 1, 64);   // combine the two 16-state halves
            v = fmaf(Dh, zz, v);
            float t3  = v * v * v;
            float arg = 0.7978845608028654f * fmaf(0.044715f, t3, v);
            float e   = __expf(2.f * arg);
            float th  = 1.f - 2.f / (e + 1.f);
            gls[q] = (_Float16)(0.5f * v * (1.f + th));
        }
        if (s == 0) {
#pragma unroll
            for (int q = 0; q < 4; q++) yo[(tt + q) * CH_ + c] = gls[q];
        }
    }
}

// ---------------- GLU GEMM: pointwise in p -> unchanged ----------------
__global__ __launch_bounds__(256) void glu_k(
    const _Float16* __restrict__ W, const _Float16* __restrict__ y16,
    const float* __restrict__ outb, const float* __restrict__ lnw,
    const float* __restrict__ lnb, float* __restrict__ hbuf)
{
    __shared__ float smem[512 * 33];
    __shared__ float red[2][8][32];
    __shared__ float mus[32], rss[32];
    _Float16* yT = (_Float16*)smem;
    float* g = smem;
    int b  = blockIdx.y;
    int l0 = blockIdx.x << 5;
    int t  = threadIdx.x;
    int lane = t & 63, wid = t >> 6;
    int l15 = lane & 15, quad = lane >> 4;
    {
        int k = t;
        const uint4* src = (const uint4*)(y16 + ((size_t)(b * H_ + k)) * L_ + l0);
        uint4 v[4];
#pragma unroll
        for (int j = 0; j < 4; j++) v[j] = src[j];
        const _Float16* hv = (const _Float16*)v;
#pragma unroll
        for (int j = 0; j < 32; j++) yT[j * 264 + k] = hv[j];
    }
    __syncthreads();
    f32x4 acc[8][2];
#pragma unroll
    for (int mt = 0; mt < 8; mt++) {
        acc[mt][0] = (f32x4){0.f, 0.f, 0.f, 0.f};
        acc[mt][1] = (f32x4){0.f, 0.f, 0.f, 0.f};
    }
#pragma unroll
    for (int ks = 0; ks < 8; ks++) {
        int kk = ks * 32 + quad * 8;
        half8 b0 = *(const half8*)&yT[l15 * 264 + kk];
        half8 b1 = *(const half8*)&yT[(16 + l15) * 264 + kk];
#pragma unroll
        for (int mt = 0; mt < 8; mt++) {
            half8 a = *(const half8*)(W + ((size_t)(wid * 128 + mt * 16 + l15)) * H_ + kk);
            acc[mt][0] = __builtin_amdgcn_mfma_f32_16x16x32_f16(a, b0, acc[mt][0], 0, 0, 0);
            acc[mt][1] = __builtin_amdgcn_mfma_f32_16x16x32_f16(a, b1, acc[mt][1], 0, 0, 0);
        }
    }
    __syncthreads();
#pragma unroll
    for (int mt = 0; mt < 8; mt++)
#pragma unroll
        for (int nt = 0; nt < 2; nt++)
#pragma unroll
            for (int r = 0; r < 4; r++)
                g[(wid * 128 + mt * 16 + quad * 4 + r) * 33 + nt * 16 + l15] = acc[mt][nt][r];
    __syncthreads();
    int l = t & 31, c0 = t >> 5;
    float u[32], s1 = 0.f, s2 = 0.f;
#pragma unroll
    for (int j = 0; j < 32; j++) {
        int ch = c0 + 8 * j;
        float g1 = g[ch * 33 + l] + outb[ch];
        float g2 = g[(ch + 256) * 33 + l] + outb[ch + 256];
        float sg = 1.f / (1.f + __expf(-g2));
        float uu = g1 * sg + hbuf[((size_t)(b * H_ + ch)) * L_ + l0 + l];
        u[j] = uu; s1 += uu; s2 = fmaf(uu, uu, s2);
    }
    red[0][c0][l] = s1; red[1][c0][l] = s2;
    __syncthreads();
    if (t < 32) {
        float a = 0.f, q = 0.f;
#pragma unroll
        for (int p = 0; p < 8; p++) { a += red[0][p][t]; q += red[1][p][t]; }
        float mu  = a * (1.f / 256.f);
        float var = q * (1.f / 256.f) - mu * mu;
        mus[t] = mu; rss[t] = rsqrtf(var + 1e-5f);
    }
    __syncthreads();
    float mu = mus[l], rs = rss[l];
#pragma unroll
    for (int j = 0; j < 32; j++) {
        int ch = c0 + 8 * j;
        hbuf[((size_t)(b * H_ + ch)) * L_ + l0 + l] = (u[j] - mu) * rs * lnw[ch] + lnb[ch];
    }
}

// ---------------- decoder: reads permuted hbuf, writes out at actual l ----------------
__global__ __launch_bounds__(256) void decoder_k(
    const float* __restrict__ hbuf, const float* __restrict__ dw,
    const float* __restrict__ db, float* __restrict__ out)
{
    __shared__ float ht[256][64];
    __shared__ float wt[DOUT * H_];
    int blk = blockIdx.x;
    int b  = blk >> 6;
    int g  = blk & 63;
    int p0 = g << 6;
    int t  = threadIdx.x;
    {
        const float4* src = (const float4*)(hbuf + ((size_t)(b * H_ + t)) * L_ + p0);
        float4* dst = (float4*)&ht[t][0];
#pragma unroll
        for (int j = 0; j < 16; j++) dst[j] = src[j];
    }
    for (int idx = t; idx < DOUT * H_; idx += 256) wt[idx] = dw[idx];
    __syncthreads();
    int j = t & 63, og = t >> 6;
    int p = p0 + j;
    int tt = p >> 5, c = p & 31;                   // l = c*T_ + tt
    size_t obase = ((size_t)(b * L_ + c * T_ + tt)) * DOUT;
    for (int o = og; o < DOUT; o += 4) {
        float a0 = 0.f, a1 = 0.f;
#pragma unroll 8
        for (int k = 0; k < H_; k += 2) {
            a0 = fmaf(ht[k][j],     wt[o * H_ + k],     a0);
            a1 = fmaf(ht[k + 1][j], wt[o * H_ + k + 1], a1);
        }
        out[obase + o] = a0 + a1 + db[o];
    }
}

extern "C" void kernel_launch(void* const* d_in, const int* in_sizes, int n_in,
                              void* d_out, int out_size, void* d_ws, size_t ws_size,
                              hipStream_t stream)
{
    (void)in_sizes; (void)n_in; (void)out_size; (void)ws_size;
    const float* x          = (const float*)d_in[0];
    const float* enc_w      = (const float*)d_in[1];
    const float* enc_b      = (const float*)d_in[2];
    const float* log_dt     = (const float*)d_in[3];
    const float* log_A_real = (const float*)d_in[4];
    const float* A_imag     = (const float*)d_in[5];
    const float* C_re       = (const float*)d_in[6];
    const float* C_im       = (const float*)d_in[7];
    const float* Dp         = (const float*)d_in[8];
    const float* out_w      = (const float*)d_in[9];
    const float* out_b      = (const float*)d_in[10];
    const float* ln_w       = (const float*)d_in[11];
    const float* ln_b       = (const float*)d_in[12];
    const float* dec_w      = (const float*)d_in[13];
    const float* dec_b      = (const float*)d_in[14];
    float* outp = (float*)d_out;

    char* ws = (char*)d_ws;
    float* hbuf = (float*)ws;      ws += (size_t)B_ * H_ * L_ * 4;
    _Float16* y16 = (_Float16*)ws; ws += (size_t)B_ * H_ * L_ * 2;
    float* F = (float*)ws;         ws += (size_t)B_ * H_ * CH_ * N_ * 2 * 4;
    size_t tb = (size_t)NL_ * H_ * N_;
    float* wre = (float*)ws; ws += tb * 4;
    float* wim = (float*)ws; ws += tb * 4;
    float* ctr = (float*)ws; ws += tb * 4;
    float* cti = (float*)ws; ws += tb * 4;
    float* wtr = (float*)ws; ws += tb * 4;
    float* wti = (float*)ws; ws += tb * 4;
    _Float16* W16 = (_Float16*)ws; ws += (size_t)NL_ * 2 * H_ * H_ * 2;

    params_k<<<(int)(tb / 256), 256, 0, stream>>>(log_dt, log_A_real, A_imag, C_re, C_im,
                                                  wre, wim, ctr, cti, wtr, wti);
    wconv_k<<<(NL_ * 2 * H_ * H_) / 256, 256, 0, stream>>>(out_w, W16);
    encoder_k<<<B_ * 64, 256, 0, stream>>>(x, enc_w, enc_b, hbuf);
    for (int i = 0; i < NL_; i++) {
        size_t o = (size_t)i * H_ * N_;
        phase1_k<<<(B_ * H_ * CH_ * 2) / 256, 256, 0, stream>>>(hbuf, wre + o, wim + o, F);
        phase2_k<<<(B_ * H_ * N_) / 256, 256, 0, stream>>>(F, wtr + o, wti + o);
        phase3_k<<<(B_ * H_ * CH_ * 2) / 256, 256, 0, stream>>>(hbuf, wre + o, wim + o, ctr + o, cti + o,
                                                                F, Dp + i * H_, y16);
        glu_k<<<dim3(L_ / 32, B_), 256, 0, stream>>>(W16 + (size_t)i * 2 * H_ * H_, y16,
                                                     out_b + i * 2 * H_, ln_w + i * H_, ln_b + i * H_, hbuf);
    }
    decoder_k<<<B_ * 64, 256, 0, stream>>>(hbuf, dec_w, dec_b, outp);
}

// Round 3
// 830.971 us; speedup vs baseline: 3.3480x; 1.5043x over previous
//
#include <hip/hip_runtime.h>
#include <hip/hip_fp16.h>

#define B_   16
#define L_   4096
#define DIN  64
#define H_   256
#define N_   32
#define NL_  4
#define DOUT 10
#define CH_  32
#define T_   128

typedef _Float16 half8 __attribute__((ext_vector_type(8)));
typedef float f32x4 __attribute__((ext_vector_type(4)));

__device__ __forceinline__ float gelu_f(float v) {
    float t3  = v * v * v;
    float arg = 0.7978845608028654f * fmaf(0.044715f, t3, v);
    float e   = __expf(2.f * arg);
    float th  = 1.f - 2.f / (e + 1.f);
    return 0.5f * v * (1.f + th);
}

// ---------------- table generation: per (layer,h) block ----------------
// G[x] = K[127-x] (+D at x=127), G[128..255]=0 ; Wv[2n][j]=Re(w^{127-j}), [2n+1]=Im
// Vt[tt][2n]=Re(C~ w^{tt+1}), [2n+1]=-Im(C~ w^{tt+1}) ; wtr/wti = w^128 for phase2
__global__ __launch_bounds__(256) void gen_k(
    const float* __restrict__ log_dt, const float* __restrict__ log_A_real,
    const float* __restrict__ A_imag, const float* __restrict__ C_re, const float* __restrict__ C_im,
    const float* __restrict__ Dp,
    _Float16* __restrict__ Wv, _Float16* __restrict__ Vt, _Float16* __restrict__ G,
    float* __restrict__ wtr, float* __restrict__ wti)
{
    __shared__ float sxr[N_], sxi[N_], scr[N_], sci[N_], skd[T_];
    int ih = blockIdx.x;
    int t  = threadIdx.x;
    if (t < N_) {
        int n = t;
        float dt  = expf(log_dt[ih]);
        float Are = -expf(log_A_real[ih * N_ + n]);
        float Aim = A_imag[ih * N_ + n];
        float xr = dt * Are, xi = dt * Aim;
        float ex = expf(xr), cy = cosf(xi), sy = sinf(xi);
        float sh = sinf(0.5f * xi);
        float em_re = expm1f(xr) * cy - 2.f * sh * sh;
        float em_im = ex * sy;
        float inv = 1.f / (Are * Are + Aim * Aim);
        float qr = (em_re * Are + em_im * Aim) * inv;
        float qi = (em_im * Are - em_re * Aim) * inv;
        float crv = C_re[ih * N_ + n], civ = C_im[ih * N_ + n];
        sxr[n] = xr; sxi[n] = xi;
        scr[n] = 2.f * (crv * qr - civ * qi);
        sci[n] = 2.f * (crv * qi + civ * qr);
        float txr = 128.f * xr, txi = 128.f * xi;
        float exT = expf(txr);
        wtr[ih * N_ + n] = exT * cosf(txi);
        wti[ih * N_ + n] = exT * sinf(txi);
    }
    __syncthreads();
    if (t <= T_) {
        int d = t;
        float fd = (float)d;
        float kd = 0.f;
        for (int n = 0; n < N_; n++) {
            float ar = expf(fd * sxr[n]);
            float ang = fd * sxi[n];
            float wdr = ar * cosf(ang), wdi = ar * sinf(ang);
            if (d < T_) {
                kd = fmaf(scr[n], wdr, kd);
                kd = fmaf(-sci[n], wdi, kd);
                Wv[((size_t)ih * 64 + 2 * n) * T_ + (127 - d)]     = (_Float16)wdr;
                Wv[((size_t)ih * 64 + 2 * n + 1) * T_ + (127 - d)] = (_Float16)wdi;
            }
            if (d >= 1) {
                float vr = scr[n] * wdr - sci[n] * wdi;
                float vi = scr[n] * wdi + sci[n] * wdr;
                Vt[((size_t)ih * T_ + (d - 1)) * 64 + 2 * n]     = (_Float16)vr;
                Vt[((size_t)ih * T_ + (d - 1)) * 64 + 2 * n + 1] = (_Float16)(-vi);
            }
        }
        if (d < T_) skd[d] = kd;
    }
    __syncthreads();
    if (t < T_) {
        float v = skd[127 - t];
        if (t == 127) v += Dp[ih];
        G[(size_t)ih * 256 + t]       = (_Float16)v;
        G[(size_t)ih * 256 + 128 + t] = (_Float16)0.f;
    }
}

__global__ __launch_bounds__(256) void wconv_k(const float* __restrict__ w, _Float16* __restrict__ w16)
{
    int idx = blockIdx.x * 256 + threadIdx.x;
    w16[idx] = (_Float16)w[idx];
}

// ---------------- encoder: natural layout, fp32 hbuf + f16 zy ----------------
__global__ __launch_bounds__(256) void encoder_k(
    const float* __restrict__ x, const float* __restrict__ ew,
    const float* __restrict__ eb, float* __restrict__ hbuf, _Float16* __restrict__ zy)
{
    __shared__ float xt[64][64];
    int blk = blockIdx.x;
    int b  = blk >> 6;
    int l0 = (blk & 63) << 6;
    int t  = threadIdx.x;
    {
        int r = t >> 2, cp = (t & 3) * 16;
        const float4* src = (const float4*)(x + ((size_t)(b * L_ + l0 + r)) * DIN + cp);
        float4* dst = (float4*)&xt[r][cp];
#pragma unroll
        for (int j = 0; j < 4; j++) dst[j] = src[j];
    }
    float wrg[64];
#pragma unroll
    for (int i = 0; i < 64; i += 4) {
        float4 wv = *(const float4*)(ew + t * 64 + i);
        wrg[i] = wv.x; wrg[i+1] = wv.y; wrg[i+2] = wv.z; wrg[i+3] = wv.w;
    }
    float bias = eb[t];
    __syncthreads();
    float* out = hbuf + ((size_t)(b * H_ + t)) * L_ + l0;
    _Float16* outz = zy + ((size_t)(b * H_ + t)) * L_ + l0;
    for (int l = 0; l < 64; l += 4) {
        float4 res;
        float* rp = (float*)&res;
        _Float16 h4[4];
#pragma unroll
        for (int q = 0; q < 4; q++) {
            float a0 = 0.f, a1 = 0.f;
#pragma unroll
            for (int i = 0; i < 64; i += 2) {
                a0 = fmaf(xt[l+q][i],   wrg[i],   a0);
                a1 = fmaf(xt[l+q][i+1], wrg[i+1], a1);
            }
            rp[q] = a0 + a1 + bias;
            h4[q] = (_Float16)rp[q];
        }
        *(float4*)(out + l) = res;
        *(uint2*)(outz + l) = *(uint2*)h4;
    }
}

// ---------------- finals GEMM: F[b,h,c][2n] = sum_j Wv[2n][j] * Z[c][j] ----------------
__global__ __launch_bounds__(256) void finals_k(
    const _Float16* __restrict__ zy, const _Float16* __restrict__ Wv,
    float* __restrict__ F)
{
    __shared__ _Float16 zb[CH_][136];
    int h = blockIdx.x, b = blockIdx.y;
    int t = threadIdx.x;
    const uint4* src = (const uint4*)(zy + ((size_t)(b * H_ + h)) * L_);
#pragma unroll
    for (int j = 0; j < 2; j++) {
        uint4 v = src[t * 2 + j];
        int e0 = (t * 2 + j) * 8;
        int c = e0 >> 7, jj = e0 & 127;
        *(uint4*)&zb[c][jj] = v;
    }
    __syncthreads();
    int lane = t & 63, w = t >> 6;
    int l15 = lane & 15, quad = lane >> 4;
    f32x4 acc[2];
    acc[0] = (f32x4){0.f,0.f,0.f,0.f};
    acc[1] = (f32x4){0.f,0.f,0.f,0.f};
    const _Float16* wvb = Wv + ((size_t)h * 64 + w * 16 + l15) * T_;
#pragma unroll
    for (int ks = 0; ks < 4; ks++) {
        int kk = ks * 32 + quad * 8;
        half8 a  = *(const half8*)(wvb + kk);
        half8 b0 = *(const half8*)&zb[l15][kk];
        half8 b1 = *(const half8*)&zb[16 + l15][kk];
        acc[0] = __builtin_amdgcn_mfma_f32_16x16x32_f16(a, b0, acc[0], 0, 0, 0);
        acc[1] = __builtin_amdgcn_mfma_f32_16x16x32_f16(a, b1, acc[1], 0, 0, 0);
    }
    float* Fb = F + ((size_t)(b * H_ + h)) * CH_ * 64;
#pragma unroll
    for (int nt = 0; nt < 2; nt++) {
        int c = nt * 16 + l15;
        *(f32x4*)(Fb + c * 64 + w * 16 + quad * 4) = acc[nt];
    }
}

// ---------------- phase 2: sequential prefix over chunks (unchanged) ----------------
__global__ __launch_bounds__(256) void phase2_k(
    float* __restrict__ F, const float* __restrict__ wtr, const float* __restrict__ wti)
{
    int tid = blockIdx.x * 256 + threadIdx.x;
    int n  = tid & (N_ - 1);
    int bh = tid >> 5;
    int hh = bh & (H_ - 1);
    float wr = wtr[hh * N_ + n], wi = wti[hh * N_ + n];
    float cr = 0.f, ci = 0.f;
    float* base = F + (size_t)bh * CH_ * 64 + 2 * n;
#pragma unroll 4
    for (int c = 0; c < CH_; c++) {
        float fr = base[c * 64], fi = base[c * 64 + 1];
        base[c * 64] = cr; base[c * 64 + 1] = ci;
        float nr = fmaf(wr, cr, fr);
        nr = fmaf(-wi, ci, nr);
        float ni = fmaf(wi, cr, fi);
        ni = fmaf(wr, ci, ni);
        cr = nr; ci = ni;
    }
}

// ---------------- conv GEMM: y = gelu( Km@Z^T + Vt@Sinit^T ), in-place zy rows ----------------
__global__ __launch_bounds__(256) void conv_k(
    const _Float16* __restrict__ zy, const _Float16* __restrict__ G,
    const _Float16* __restrict__ Vt, const float* __restrict__ F,
    _Float16* __restrict__ yo)
{
    __shared__ _Float16 zT[128][136];   // r x j   34.8 KB
    __shared__ _Float16 Ff[128][72];    // r x 2n  18.4 KB
    __shared__ _Float16 Gs[256];
    int h = blockIdx.x, rb = blockIdx.y;
    int t = threadIdx.x;
    int b0 = rb * 4;
    // stage Z: 4 (b,h) rows x 4096 f16, fully coalesced
#pragma unroll
    for (int q = 0; q < 8; q++) {
        int idx = q * 256 + t;
        int brow = idx >> 9;
        int e = (idx & 511) * 8;
        uint4 v = *(const uint4*)(zy + ((size_t)((b0 + brow) * H_ + h)) * L_ + e);
        int c = e >> 7, jj = e & 127;
        *(uint4*)&zT[brow * 32 + c][jj] = v;
    }
    // stage F (fp32 -> f16): 128 r x 64
#pragma unroll
    for (int q = 0; q < 8; q++) {
        int idx = q * 256 + t;
        int r = idx >> 4;
        int k4 = (idx & 15) * 4;
        int brow = r >> 5, c = r & 31;
        float4 v = *(const float4*)(F + (((size_t)((b0 + brow) * H_ + h)) * CH_ + c) * 64 + k4);
        _Float16 tmp[4] = {(_Float16)v.x, (_Float16)v.y, (_Float16)v.z, (_Float16)v.w};
        *(uint2*)&Ff[r][k4] = *(uint2*)tmp;
    }
    Gs[t] = G[(size_t)h * 256 + t];
    __syncthreads();
    int lane = t & 63, w = t >> 6;
    int l15 = lane & 15, quad = lane >> 4;
    f32x4 acc[2][8];
#pragma unroll
    for (int mt = 0; mt < 2; mt++)
#pragma unroll
        for (int nt = 0; nt < 8; nt++) acc[mt][nt] = (f32x4){0.f,0.f,0.f,0.f};
    // main conv: A[m=tt][k=j] = Km[tt][j] = Gs[127-tt+j]
#pragma unroll
    for (int ks = 0; ks < 4; ks++) {
        int kk = ks * 32 + quad * 8;
        int base0 = 127 - (w * 32 + l15) + kk;
        int base1 = base0 - 16;
        half8 a0, a1;
#pragma unroll
        for (int j = 0; j < 8; j++) { a0[j] = Gs[base0 + j]; a1[j] = Gs[base1 + j]; }
#pragma unroll
        for (int nt = 0; nt < 8; nt++) {
            half8 bf = *(const half8*)&zT[nt * 16 + l15][kk];
            acc[0][nt] = __builtin_amdgcn_mfma_f32_16x16x32_f16(a0, bf, acc[0][nt], 0, 0, 0);
            acc[1][nt] = __builtin_amdgcn_mfma_f32_16x16x32_f16(a1, bf, acc[1][nt], 0, 0, 0);
        }
    }
    // correction: A[m=tt][k=2n] = Vt[tt][2n], B[n=r][k=2n] = Sinit
    const _Float16* vb = Vt + (size_t)h * T_ * 64;
#pragma unroll
    for (int ks = 0; ks < 2; ks++) {
        int kk = ks * 32 + quad * 8;
        half8 a0 = *(const half8*)(vb + ((size_t)(w * 32 + l15)) * 64 + kk);
        half8 a1 = *(const half8*)(vb + ((size_t)(w * 32 + 16 + l15)) * 64 + kk);
#pragma unroll
        for (int nt = 0; nt < 8; nt++) {
            half8 bf = *(const half8*)&Ff[nt * 16 + l15][kk];
            acc[0][nt] = __builtin_amdgcn_mfma_f32_16x16x32_f16(a0, bf, acc[0][nt], 0, 0, 0);
            acc[1][nt] = __builtin_amdgcn_mfma_f32_16x16x32_f16(a1, bf, acc[1][nt], 0, 0, 0);
        }
    }
    __syncthreads();   // zT reads done; reuse as output tile [r][tt]
#pragma unroll
    for (int mt = 0; mt < 2; mt++)
#pragma unroll
        for (int nt = 0; nt < 8; nt++) {
            int r = nt * 16 + l15;
            int tt0 = w * 32 + mt * 16 + quad * 4;
            _Float16 o[4];
#pragma unroll
            for (int rr = 0; rr < 4; rr++) o[rr] = (_Float16)gelu_f(acc[mt][nt][rr]);
            *(uint2*)&zT[r][tt0] = *(uint2*)o;
        }
    __syncthreads();
#pragma unroll
    for (int q = 0; q < 8; q++) {
        int idx = q * 256 + t;
        int brow = idx >> 9;
        int e = (idx & 511) * 8;
        int c = e >> 7, jj = e & 127;
        uint4 v = *(uint4*)&zT[brow * 32 + c][jj];
        *(uint4*)(yo + ((size_t)((b0 + brow) * H_ + h)) * L_ + e) = v;
    }
}

// ---------------- GLU GEMM + residual + LN; writes hbuf (fp32) and zy (f16, next-layer input) ----------------
__global__ __launch_bounds__(256) void glu_k(
    const _Float16* __restrict__ W, const _Float16* __restrict__ y16,
    const float* __restrict__ outb, const float* __restrict__ lnw,
    const float* __restrict__ lnb, float* __restrict__ hbuf, _Float16* __restrict__ z16o)
{
    __shared__ float smem[512 * 33];
    __shared__ float red[2][8][32];
    __shared__ float mus[32], rss[32];
    _Float16* yT = (_Float16*)smem;
    float* g = smem;
    int b  = blockIdx.y;
    int l0 = blockIdx.x << 5;
    int t  = threadIdx.x;
    int lane = t & 63, wid = t >> 6;
    int l15 = lane & 15, quad = lane >> 4;
    {
        int k = t;
        const uint4* src = (const uint4*)(y16 + ((size_t)(b * H_ + k)) * L_ + l0);
        uint4 v[4];
#pragma unroll
        for (int j = 0; j < 4; j++) v[j] = src[j];
        const _Float16* hv = (const _Float16*)v;
#pragma unroll
        for (int j = 0; j < 32; j++) yT[j * 264 + k] = hv[j];
    }
    __syncthreads();
    f32x4 acc[8][2];
#pragma unroll
    for (int mt = 0; mt < 8; mt++) {
        acc[mt][0] = (f32x4){0.f,0.f,0.f,0.f};
        acc[mt][1] = (f32x4){0.f,0.f,0.f,0.f};
    }
#pragma unroll
    for (int ks = 0; ks < 8; ks++) {
        int kk = ks * 32 + quad * 8;
        half8 b0 = *(const half8*)&yT[l15 * 264 + kk];
        half8 b1 = *(const half8*)&yT[(16 + l15) * 264 + kk];
#pragma unroll
        for (int mt = 0; mt < 8; mt++) {
            half8 a = *(const half8*)(W + ((size_t)(wid * 128 + mt * 16 + l15)) * H_ + kk);
            acc[mt][0] = __builtin_amdgcn_mfma_f32_16x16x32_f16(a, b0, acc[mt][0], 0, 0, 0);
            acc[mt][1] = __builtin_amdgcn_mfma_f32_16x16x32_f16(a, b1, acc[mt][1], 0, 0, 0);
        }
    }
    __syncthreads();
#pragma unroll
    for (int mt = 0; mt < 8; mt++)
#pragma unroll
        for (int nt = 0; nt < 2; nt++)
#pragma unroll
            for (int r = 0; r < 4; r++)
                g[(wid * 128 + mt * 16 + quad * 4 + r) * 33 + nt * 16 + l15] = acc[mt][nt][r];
    __syncthreads();
    int l = t & 31, c0 = t >> 5;
    float u[32], s1 = 0.f, s2 = 0.f;
#pragma unroll
    for (int j = 0; j < 32; j++) {
        int ch = c0 + 8 * j;
        float g1 = g[ch * 33 + l] + outb[ch];
        float g2 = g[(ch + 256) * 33 + l] + outb[ch + 256];
        float sg = 1.f / (1.f + __expf(-g2));
        float uu = g1 * sg + hbuf[((size_t)(b * H_ + ch)) * L_ + l0 + l];
        u[j] = uu; s1 += uu; s2 = fmaf(uu, uu, s2);
    }
    red[0][c0][l] = s1; red[1][c0][l] = s2;
    __syncthreads();
    if (t < 32) {
        float a = 0.f, q = 0.f;
#pragma unroll
        for (int p = 0; p < 8; p++) { a += red[0][p][t]; q += red[1][p][t]; }
        float mu  = a * (1.f / 256.f);
        float var = q * (1.f / 256.f) - mu * mu;
        mus[t] = mu; rss[t] = rsqrtf(var + 1e-5f);
    }
    __syncthreads();
    float mu = mus[l], rs = rss[l];
#pragma unroll
    for (int j = 0; j < 32; j++) {
        int ch = c0 + 8 * j;
        float vv = (u[j] - mu) * rs * lnw[ch] + lnb[ch];
        size_t off = ((size_t)(b * H_ + ch)) * L_ + l0 + l;
        hbuf[off] = vv;
        z16o[off] = (_Float16)vv;
    }
}

// ---------------- decoder: natural layout ----------------
__global__ __launch_bounds__(256) void decoder_k(
    const float* __restrict__ hbuf, const float* __restrict__ dw,
    const float* __restrict__ db, float* __restrict__ out)
{
    __shared__ float ht[256][64];
    __shared__ float wt[DOUT * H_];
    int blk = blockIdx.x;
    int b  = blk >> 6;
    int l0 = (blk & 63) << 6;
    int t  = threadIdx.x;
    {
        const float4* src = (const float4*)(hbuf + ((size_t)(b * H_ + t)) * L_ + l0);
        float4* dst = (float4*)&ht[t][0];
#pragma unroll
        for (int j = 0; j < 16; j++) dst[j] = src[j];
    }
    for (int idx = t; idx < DOUT * H_; idx += 256) wt[idx] = dw[idx];
    __syncthreads();
    int l = t & 63, og = t >> 6;
    for (int o = og; o < DOUT; o += 4) {
        float a0 = 0.f, a1 = 0.f;
#pragma unroll 8
        for (int k = 0; k < H_; k += 2) {
            a0 = fmaf(ht[k][l],     wt[o * H_ + k],     a0);
            a1 = fmaf(ht[k + 1][l], wt[o * H_ + k + 1], a1);
        }
        out[((size_t)(b * L_ + l0 + l)) * DOUT + o] = a0 + a1 + db[o];
    }
}

extern "C" void kernel_launch(void* const* d_in, const int* in_sizes, int n_in,
                              void* d_out, int out_size, void* d_ws, size_t ws_size,
                              hipStream_t stream)
{
    (void)in_sizes; (void)n_in; (void)out_size; (void)ws_size;
    const float* x          = (const float*)d_in[0];
    const float* enc_w      = (const float*)d_in[1];
    const float* enc_b      = (const float*)d_in[2];
    const float* log_dt     = (const float*)d_in[3];
    const float* log_A_real = (const float*)d_in[4];
    const float* A_imag     = (const float*)d_in[5];
    const float* C_re       = (const float*)d_in[6];
    const float* C_im       = (const float*)d_in[7];
    const float* Dp         = (const float*)d_in[8];
    const float* out_w      = (const float*)d_in[9];
    const float* out_b      = (const float*)d_in[10];
    const float* ln_w       = (const float*)d_in[11];
    const float* ln_b       = (const float*)d_in[12];
    const float* dec_w      = (const float*)d_in[13];
    const float* dec_b      = (const float*)d_in[14];
    float* outp = (float*)d_out;

    char* ws = (char*)d_ws;
    float* hbuf = (float*)ws;      ws += (size_t)B_ * H_ * L_ * 4;               // 64 MB
    _Float16* zy = (_Float16*)ws;  ws += (size_t)B_ * H_ * L_ * 2;               // 32 MB (z16 & y16 aliased)
    float* F = (float*)ws;         ws += (size_t)B_ * H_ * CH_ * 64 * 4;         // 33.5 MB
    _Float16* Wv = (_Float16*)ws;  ws += (size_t)NL_ * H_ * 64 * T_ * 2;         // 8.4 MB
    _Float16* Vt = (_Float16*)ws;  ws += (size_t)NL_ * H_ * T_ * 64 * 2;         // 8.4 MB
    _Float16* G  = (_Float16*)ws;  ws += (size_t)NL_ * H_ * 256 * 2;             // 0.5 MB
    size_t tb = (size_t)NL_ * H_ * N_;
    float* wtr = (float*)ws; ws += tb * 4;
    float* wti = (float*)ws; ws += tb * 4;
    _Float16* W16 = (_Float16*)ws; ws += (size_t)NL_ * 2 * H_ * H_ * 2;          // 1 MB

    gen_k<<<NL_ * H_, 256, 0, stream>>>(log_dt, log_A_real, A_imag, C_re, C_im, Dp,
                                        Wv, Vt, G, wtr, wti);
    wconv_k<<<(NL_ * 2 * H_ * H_) / 256, 256, 0, stream>>>(out_w, W16);
    encoder_k<<<B_ * 64, 256, 0, stream>>>(x, enc_w, enc_b, hbuf, zy);
    for (int i = 0; i < NL_; i++) {
        size_t th = (size_t)i * H_;
        finals_k<<<dim3(H_, B_), 256, 0, stream>>>(zy, Wv + th * 64 * T_, F);
        phase2_k<<<(B_ * H_ * N_) / 256, 256, 0, stream>>>(F, wtr + th * N_, wti + th * N_);
        conv_k<<<dim3(H_, B_ / 4), 256, 0, stream>>>(zy, G + th * 256, Vt + th * T_ * 64, F, zy);
        glu_k<<<dim3(L_ / 32, B_), 256, 0, stream>>>(W16 + (size_t)i * 2 * H_ * H_, zy,
                                                     out_b + i * 2 * H_, ln_w + th, ln_b + th,
                                                     hbuf, zy);
    }
    decoder_k<<<B_ * 64, 256, 0, stream>>>(hbuf, dec_w, dec_b, outp);
}

// Round 4
// 611.142 us; speedup vs baseline: 4.5523x; 1.3597x over previous
//
#include <hip/hip_runtime.h>
#include <hip/hip_fp16.h>

#define B_   16
#define L_   4096
#define DIN  64
#define H_   256
#define N_   32
#define NL_  4
#define DOUT 10
#define CH_  32
#define T_   128

typedef _Float16 half8 __attribute__((ext_vector_type(8)));
typedef float f32x4 __attribute__((ext_vector_type(4)));

__device__ __forceinline__ float gelu_f(float v) {
    float t3  = v * v * v;
    float arg = 0.7978845608028654f * fmaf(0.044715f, t3, v);
    float e   = __expf(2.f * arg);
    float th  = 1.f - 2.f / (e + 1.f);
    return 0.5f * v * (1.f + th);
}

// ---------------- table generation: per (layer,h) block ----------------
__global__ __launch_bounds__(256) void gen_k(
    const float* __restrict__ log_dt, const float* __restrict__ log_A_real,
    const float* __restrict__ A_imag, const float* __restrict__ C_re, const float* __restrict__ C_im,
    const float* __restrict__ Dp,
    _Float16* __restrict__ Wv, _Float16* __restrict__ Vt, _Float16* __restrict__ G,
    float* __restrict__ wtr, float* __restrict__ wti)
{
    __shared__ float sxr[N_], sxi[N_], scr[N_], sci[N_], skd[T_];
    int ih = blockIdx.x;
    int t  = threadIdx.x;
    if (t < N_) {
        int n = t;
        float dt  = expf(log_dt[ih]);
        float Are = -expf(log_A_real[ih * N_ + n]);
        float Aim = A_imag[ih * N_ + n];
        float xr = dt * Are, xi = dt * Aim;
        float ex = expf(xr), cy = cosf(xi), sy = sinf(xi);
        float sh = sinf(0.5f * xi);
        float em_re = expm1f(xr) * cy - 2.f * sh * sh;
        float em_im = ex * sy;
        float inv = 1.f / (Are * Are + Aim * Aim);
        float qr = (em_re * Are + em_im * Aim) * inv;
        float qi = (em_im * Are - em_re * Aim) * inv;
        float crv = C_re[ih * N_ + n], civ = C_im[ih * N_ + n];
        sxr[n] = xr; sxi[n] = xi;
        scr[n] = 2.f * (crv * qr - civ * qi);
        sci[n] = 2.f * (crv * qi + civ * qr);
        float txr = 128.f * xr, txi = 128.f * xi;
        float exT = expf(txr);
        wtr[ih * N_ + n] = exT * cosf(txi);
        wti[ih * N_ + n] = exT * sinf(txi);
    }
    __syncthreads();
    if (t <= T_) {
        int d = t;
        float fd = (float)d;
        float kd = 0.f;
        for (int n = 0; n < N_; n++) {
            float ar = expf(fd * sxr[n]);
            float ang = fd * sxi[n];
            float wdr = ar * cosf(ang), wdi = ar * sinf(ang);
            if (d < T_) {
                kd = fmaf(scr[n], wdr, kd);
                kd = fmaf(-sci[n], wdi, kd);
                Wv[((size_t)ih * 64 + 2 * n) * T_ + (127 - d)]     = (_Float16)wdr;
                Wv[((size_t)ih * 64 + 2 * n + 1) * T_ + (127 - d)] = (_Float16)wdi;
            }
            if (d >= 1) {
                float vr = scr[n] * wdr - sci[n] * wdi;
                float vi = scr[n] * wdi + sci[n] * wdr;
                Vt[((size_t)ih * T_ + (d - 1)) * 64 + 2 * n]     = (_Float16)vr;
                Vt[((size_t)ih * T_ + (d - 1)) * 64 + 2 * n + 1] = (_Float16)(-vi);
            }
        }
        if (d < T_) skd[d] = kd;
    }
    __syncthreads();
    if (t < T_) {
        float v = skd[127 - t];
        if (t == 127) v += Dp[ih];
        G[(size_t)ih * 256 + t]       = (_Float16)v;
        G[(size_t)ih * 256 + 128 + t] = (_Float16)0.f;
    }
}

__global__ __launch_bounds__(256) void wconv_k(const float* __restrict__ w, _Float16* __restrict__ w16)
{
    int idx = blockIdx.x * 256 + threadIdx.x;
    w16[idx] = (_Float16)w[idx];
}

// ---------------- encoder: writes f16 z16 only ----------------
__global__ __launch_bounds__(256) void encoder_k(
    const float* __restrict__ x, const float* __restrict__ ew,
    const float* __restrict__ eb, _Float16* __restrict__ z16)
{
    __shared__ float xt[64][64];
    int blk = blockIdx.x;
    int b  = blk >> 6;
    int l0 = (blk & 63) << 6;
    int t  = threadIdx.x;
    {
        int r = t >> 2, cp = (t & 3) * 16;
        const float4* src = (const float4*)(x + ((size_t)(b * L_ + l0 + r)) * DIN + cp);
        float4* dst = (float4*)&xt[r][cp];
#pragma unroll
        for (int j = 0; j < 4; j++) dst[j] = src[j];
    }
    float wrg[64];
#pragma unroll
    for (int i = 0; i < 64; i += 4) {
        float4 wv = *(const float4*)(ew + t * 64 + i);
        wrg[i] = wv.x; wrg[i+1] = wv.y; wrg[i+2] = wv.z; wrg[i+3] = wv.w;
    }
    float bias = eb[t];
    __syncthreads();
    _Float16* outz = z16 + ((size_t)(b * H_ + t)) * L_ + l0;
    for (int l = 0; l < 64; l += 4) {
        _Float16 h4[4];
#pragma unroll
        for (int q = 0; q < 4; q++) {
            float a0 = 0.f, a1 = 0.f;
#pragma unroll
            for (int i = 0; i < 64; i += 2) {
                a0 = fmaf(xt[l+q][i],   wrg[i],   a0);
                a1 = fmaf(xt[l+q][i+1], wrg[i+1], a1);
            }
            h4[q] = (_Float16)(a0 + a1 + bias);
        }
        *(uint2*)(outz + l) = *(uint2*)h4;
    }
}

// ---------------- finals + fused chunk-prefix: emits f16 chunk-initial states ----------------
__global__ __launch_bounds__(256) void finals_k(
    const _Float16* __restrict__ z16, const _Float16* __restrict__ Wv,
    const float* __restrict__ wtr, const float* __restrict__ wti,
    _Float16* __restrict__ Sinit)
{
    __shared__ _Float16 zb[CH_][136];
    __shared__ float Fs[CH_][68];
    int h = blockIdx.x, b = blockIdx.y;
    int t = threadIdx.x;
    const uint4* src = (const uint4*)(z16 + ((size_t)(b * H_ + h)) * L_);
#pragma unroll
    for (int j = 0; j < 2; j++) {
        uint4 v = src[t * 2 + j];
        int e0 = (t * 2 + j) * 8;
        *(uint4*)&zb[e0 >> 7][e0 & 127] = v;
    }
    __syncthreads();
    int lane = t & 63, w = t >> 6;
    int l15 = lane & 15, quad = lane >> 4;
    f32x4 acc[2];
    acc[0] = (f32x4){0.f,0.f,0.f,0.f};
    acc[1] = (f32x4){0.f,0.f,0.f,0.f};
    const _Float16* wvb = Wv + ((size_t)h * 64 + w * 16 + l15) * T_;
#pragma unroll
    for (int ks = 0; ks < 4; ks++) {
        int kk = ks * 32 + quad * 8;
        half8 a  = *(const half8*)(wvb + kk);
        half8 b0 = *(const half8*)&zb[l15][kk];
        half8 b1 = *(const half8*)&zb[16 + l15][kk];
        acc[0] = __builtin_amdgcn_mfma_f32_16x16x32_f16(a, b0, acc[0], 0, 0, 0);
        acc[1] = __builtin_amdgcn_mfma_f32_16x16x32_f16(a, b1, acc[1], 0, 0, 0);
    }
#pragma unroll
    for (int nt = 0; nt < 2; nt++) {
        int c = nt * 16 + l15;
        *(f32x4*)&Fs[c][w * 16 + quad * 4] = acc[nt];
    }
    __syncthreads();
    if (t < N_) {
        int n = t;
        float wr = wtr[h * N_ + n], wi = wti[h * N_ + n];
        float cr = 0.f, ci = 0.f;
        _Float16* sb = Sinit + ((size_t)(b * H_ + h)) * (CH_ * 64) + 2 * n;
        for (int c = 0; c < CH_; c++) {
            float2 f2 = *(const float2*)&Fs[c][2 * n];
            union { unsigned u; _Float16 hf[2]; } p;
            p.hf[0] = (_Float16)cr; p.hf[1] = (_Float16)ci;
            *(unsigned*)(sb + (size_t)c * 64) = p.u;
            float nr = fmaf(wr, cr, f2.x);
            nr = fmaf(-wi, ci, nr);
            float ni = fmaf(wi, cr, f2.y);
            ni = fmaf(wr, ci, ni);
            cr = nr; ci = ni;
        }
    }
}

// ---------------- conv GEMM: y = gelu( Km@Z^T + Vt@Sinit^T ) -> y16 ----------------
__global__ __launch_bounds__(256) void conv_k(
    const _Float16* __restrict__ z16, const _Float16* __restrict__ G,
    const _Float16* __restrict__ Vt, const _Float16* __restrict__ Sinit,
    _Float16* __restrict__ y16)
{
    __shared__ _Float16 zT[128][136];
    __shared__ _Float16 Ff[128][72];
    __shared__ _Float16 Gs[256];
    int h = blockIdx.x, rb = blockIdx.y;
    int t = threadIdx.x;
    int b0 = rb * 4;
#pragma unroll
    for (int q = 0; q < 8; q++) {
        int idx = q * 256 + t;
        int brow = idx >> 9;
        int e = (idx & 511) * 8;
        uint4 v = *(const uint4*)(z16 + ((size_t)((b0 + brow) * H_ + h)) * L_ + e);
        int c = e >> 7, jj = e & 127;
        *(uint4*)&zT[brow * 32 + c][jj] = v;
    }
#pragma unroll
    for (int q = 0; q < 4; q++) {
        int idx = q * 256 + t;
        int e0 = idx * 8;
        int brow = e0 >> 11;
        int off = e0 & 2047;
        uint4 v = *(const uint4*)(Sinit + ((size_t)((b0 + brow) * H_ + h)) * (CH_ * 64) + off);
        int r = brow * 32 + (off >> 6), k = off & 63;
        *(uint4*)&Ff[r][k] = v;
    }
    Gs[t] = G[(size_t)h * 256 + t];
    __syncthreads();
    int lane = t & 63, w = t >> 6;
    int l15 = lane & 15, quad = lane >> 4;
    f32x4 acc[2][8];
#pragma unroll
    for (int mt = 0; mt < 2; mt++)
#pragma unroll
        for (int nt = 0; nt < 8; nt++) acc[mt][nt] = (f32x4){0.f,0.f,0.f,0.f};
#pragma unroll
    for (int ks = 0; ks < 4; ks++) {
        int kk = ks * 32 + quad * 8;
        int base0 = 127 - (w * 32 + l15) + kk;
        int base1 = base0 - 16;
        half8 a0, a1;
#pragma unroll
        for (int j = 0; j < 8; j++) { a0[j] = Gs[base0 + j]; a1[j] = Gs[base1 + j]; }
#pragma unroll
        for (int nt = 0; nt < 8; nt++) {
            half8 bf = *(const half8*)&zT[nt * 16 + l15][kk];
            acc[0][nt] = __builtin_amdgcn_mfma_f32_16x16x32_f16(a0, bf, acc[0][nt], 0, 0, 0);
            acc[1][nt] = __builtin_amdgcn_mfma_f32_16x16x32_f16(a1, bf, acc[1][nt], 0, 0, 0);
        }
    }
    const _Float16* vb = Vt + (size_t)h * T_ * 64;
#pragma unroll
    for (int ks = 0; ks < 2; ks++) {
        int kk = ks * 32 + quad * 8;
        half8 a0 = *(const half8*)(vb + ((size_t)(w * 32 + l15)) * 64 + kk);
        half8 a1 = *(const half8*)(vb + ((size_t)(w * 32 + 16 + l15)) * 64 + kk);
#pragma unroll
        for (int nt = 0; nt < 8; nt++) {
            half8 bf = *(const half8*)&Ff[nt * 16 + l15][kk];
            acc[0][nt] = __builtin_amdgcn_mfma_f32_16x16x32_f16(a0, bf, acc[0][nt], 0, 0, 0);
            acc[1][nt] = __builtin_amdgcn_mfma_f32_16x16x32_f16(a1, bf, acc[1][nt], 0, 0, 0);
        }
    }
    __syncthreads();
#pragma unroll
    for (int mt = 0; mt < 2; mt++)
#pragma unroll
        for (int nt = 0; nt < 8; nt++) {
            int r = nt * 16 + l15;
            int tt0 = w * 32 + mt * 16 + quad * 4;
            _Float16 o[4];
#pragma unroll
            for (int rr = 0; rr < 4; rr++) o[rr] = (_Float16)gelu_f(acc[mt][nt][rr]);
            *(uint2*)&zT[r][tt0] = *(uint2*)o;
        }
    __syncthreads();
#pragma unroll
    for (int q = 0; q < 8; q++) {
        int idx = q * 256 + t;
        int brow = idx >> 9;
        int e = (idx & 511) * 8;
        int c = e >> 7, jj = e & 127;
        uint4 v = *(uint4*)&zT[brow * 32 + c][jj];
        *(uint4*)(y16 + ((size_t)((b0 + brow) * H_ + h)) * L_ + e) = v;
    }
}

// ---------------- GLU GEMM (M=512, N=64) + residual + LN, f16 in/out ----------------
__global__ __launch_bounds__(256, 2) void glu_k(
    const _Float16* __restrict__ W, const _Float16* __restrict__ y16,
    const float* __restrict__ outb, const float* __restrict__ lnw,
    const float* __restrict__ lnb, _Float16* __restrict__ z16)
{
    __shared__ float u_s[256 * 66];                 // 67.6 KB; union: yT f16 [64][264] during K-loop
    __shared__ float red[2][4][64];
    __shared__ float mus[64], rss[64];
    _Float16* yT = (_Float16*)u_s;
    int b  = blockIdx.y;
    int l0 = blockIdx.x << 6;
    int t  = threadIdx.x;
    int lane = t & 63, wid = t >> 6;
    int l15 = lane & 15, quad = lane >> 4;
    // stage yT[l][ch] = y16[b, ch=t, l0+l]
    {
        const uint4* src = (const uint4*)(y16 + ((size_t)(b * H_ + t)) * L_ + l0);
        uint4 v[8];
#pragma unroll
        for (int j = 0; j < 8; j++) v[j] = src[j];
        const _Float16* hv = (const _Float16*)v;
#pragma unroll
        for (int j = 0; j < 64; j++) yT[j * 264 + t] = hv[j];
    }
    __syncthreads();
    f32x4 acc[8][4];
#pragma unroll
    for (int mt = 0; mt < 8; mt++)
#pragma unroll
        for (int nt = 0; nt < 4; nt++) acc[mt][nt] = (f32x4){0.f,0.f,0.f,0.f};
#pragma unroll
    for (int ks = 0; ks < 8; ks++) {
        int kk = ks * 32 + quad * 8;
        half8 bf[4];
#pragma unroll
        for (int nt = 0; nt < 4; nt++) bf[nt] = *(const half8*)&yT[(nt * 16 + l15) * 264 + kk];
#pragma unroll
        for (int mt = 0; mt < 8; mt++) {
            int row = (mt >> 2) * 256 + wid * 64 + (mt & 3) * 16 + l15;
            half8 a = *(const half8*)(W + (size_t)row * H_ + kk);
#pragma unroll
            for (int nt = 0; nt < 4; nt++)
                acc[mt][nt] = __builtin_amdgcn_mfma_f32_16x16x32_f16(a, bf[nt], acc[mt][nt], 0, 0, 0);
        }
    }
    __syncthreads();                                // yT dead; reuse as u
    // GLU in-register: warp holds g1 rows (mt<4) and matching g2 rows (mt+4)
#pragma unroll
    for (int mt = 0; mt < 4; mt++) {
        int chb = wid * 64 + mt * 16 + quad * 4;
        float4 ob1 = *(const float4*)(outb + chb);
        float4 ob2 = *(const float4*)(outb + 256 + chb);
        const float* o1 = (const float*)&ob1;
        const float* o2 = (const float*)&ob2;
#pragma unroll
        for (int nt = 0; nt < 4; nt++) {
            int l = nt * 16 + l15;
#pragma unroll
            for (int r = 0; r < 4; r++) {
                float g1 = acc[mt][nt][r] + o1[r];
                float g2 = acc[mt + 4][nt][r] + o2[r];
                float sg = 1.f / (1.f + __expf(-g2));
                u_s[(chb + r) * 66 + l] = g1 * sg;
            }
        }
    }
    __syncthreads();
    // residual add (coalesced z16 read) + LN sums
    int lr = t & 63, grp = t >> 6;
    float s1 = 0.f, s2 = 0.f;
    for (int j = 0; j < 64; j++) {
        int ch = grp * 64 + j;
        float uu = u_s[ch * 66 + lr] + (float)z16[((size_t)(b * H_ + ch)) * L_ + l0 + lr];
        u_s[ch * 66 + lr] = uu;
        s1 += uu; s2 = fmaf(uu, uu, s2);
    }
    red[0][grp][lr] = s1; red[1][grp][lr] = s2;
    __syncthreads();
    if (t < 64) {
        float a = red[0][0][t] + red[0][1][t] + red[0][2][t] + red[0][3][t];
        float q = red[1][0][t] + red[1][1][t] + red[1][2][t] + red[1][3][t];
        float mu  = a * (1.f / 256.f);
        float var = q * (1.f / 256.f) - mu * mu;
        mus[t] = mu; rss[t] = rsqrtf(var + 1e-5f);
    }
    __syncthreads();
    int lg = (t & 15) * 4, ch0 = t >> 4;
    float mu4[4], rs4[4];
#pragma unroll
    for (int i = 0; i < 4; i++) { mu4[i] = mus[lg + i]; rs4[i] = rss[lg + i]; }
#pragma unroll
    for (int j = 0; j < 16; j++) {
        int ch = ch0 + 16 * j;
        float wv = lnw[ch], bv = lnb[ch];
        _Float16 o4[4];
#pragma unroll
        for (int i = 0; i < 4; i++) {
            float vv = (u_s[ch * 66 + lg + i] - mu4[i]) * rs4[i] * wv + bv;
            o4[i] = (_Float16)vv;
        }
        *(uint2*)(z16 + ((size_t)(b * H_ + ch)) * L_ + l0 + lg) = *(uint2*)o4;
    }
}

// ---------------- decoder: f16 input ----------------
__global__ __launch_bounds__(256) void decoder_k(
    const _Float16* __restrict__ z16, const float* __restrict__ dw,
    const float* __restrict__ db, float* __restrict__ out)
{
    __shared__ float ht[256][65];
    __shared__ float wt[DOUT * H_];
    int blk = blockIdx.x;
    int b  = blk >> 6;
    int l0 = (blk & 63) << 6;
    int t  = threadIdx.x;
    {
        const uint4* src = (const uint4*)(z16 + ((size_t)(b * H_ + t)) * L_ + l0);
        uint4 v[8];
#pragma unroll
        for (int j = 0; j < 8; j++) v[j] = src[j];
        const _Float16* hv = (const _Float16*)v;
#pragma unroll
        for (int j = 0; j < 64; j++) ht[t][j] = (float)hv[j];
    }
    for (int idx = t; idx < DOUT * H_; idx += 256) wt[idx] = dw[idx];
    __syncthreads();
    int l = t & 63, og = t >> 6;
    for (int o = og; o < DOUT; o += 4) {
        float a0 = 0.f, a1 = 0.f;
#pragma unroll 8
        for (int k = 0; k < H_; k += 2) {
            a0 = fmaf(ht[k][l],     wt[o * H_ + k],     a0);
            a1 = fmaf(ht[k + 1][l], wt[o * H_ + k + 1], a1);
        }
        out[((size_t)(b * L_ + l0 + l)) * DOUT + o] = a0 + a1 + db[o];
    }
}

extern "C" void kernel_launch(void* const* d_in, const int* in_sizes, int n_in,
                              void* d_out, int out_size, void* d_ws, size_t ws_size,
                              hipStream_t stream)
{
    (void)in_sizes; (void)n_in; (void)out_size; (void)ws_size;
    const float* x          = (const float*)d_in[0];
    const float* enc_w      = (const float*)d_in[1];
    const float* enc_b      = (const float*)d_in[2];
    const float* log_dt     = (const float*)d_in[3];
    const float* log_A_real = (const float*)d_in[4];
    const float* A_imag     = (const float*)d_in[5];
    const float* C_re       = (const float*)d_in[6];
    const float* C_im       = (const float*)d_in[7];
    const float* Dp         = (const float*)d_in[8];
    const float* out_w      = (const float*)d_in[9];
    const float* out_b      = (const float*)d_in[10];
    const float* ln_w       = (const float*)d_in[11];
    const float* ln_b       = (const float*)d_in[12];
    const float* dec_w      = (const float*)d_in[13];
    const float* dec_b      = (const float*)d_in[14];
    float* outp = (float*)d_out;

    char* ws = (char*)d_ws;
    _Float16* z16 = (_Float16*)ws;   ws += (size_t)B_ * H_ * L_ * 2;             // 32 MB residual stream
    _Float16* y16 = (_Float16*)ws;   ws += (size_t)B_ * H_ * L_ * 2;             // 32 MB conv output
    _Float16* Sinit = (_Float16*)ws; ws += (size_t)B_ * H_ * CH_ * 64 * 2;       // 16.8 MB
    _Float16* Wv = (_Float16*)ws;    ws += (size_t)NL_ * H_ * 64 * T_ * 2;       // 8.4 MB
    _Float16* Vt = (_Float16*)ws;    ws += (size_t)NL_ * H_ * T_ * 64 * 2;       // 8.4 MB
    _Float16* G  = (_Float16*)ws;    ws += (size_t)NL_ * H_ * 256 * 2;           // 0.5 MB
    size_t tb = (size_t)NL_ * H_ * N_;
    float* wtr = (float*)ws; ws += tb * 4;
    float* wti = (float*)ws; ws += tb * 4;
    _Float16* W16 = (_Float16*)ws; ws += (size_t)NL_ * 2 * H_ * H_ * 2;          // 1 MB

    gen_k<<<NL_ * H_, 256, 0, stream>>>(log_dt, log_A_real, A_imag, C_re, C_im, Dp,
                                        Wv, Vt, G, wtr, wti);
    wconv_k<<<(NL_ * 2 * H_ * H_) / 256, 256, 0, stream>>>(out_w, W16);
    encoder_k<<<B_ * 64, 256, 0, stream>>>(x, enc_w, enc_b, z16);
    for (int i = 0; i < NL_; i++) {
        size_t th = (size_t)i * H_;
        finals_k<<<dim3(H_, B_), 256, 0, stream>>>(z16, Wv + th * 64 * T_,
                                                   wtr + th * N_, wti + th * N_, Sinit);
        conv_k<<<dim3(H_, B_ / 4), 256, 0, stream>>>(z16, G + th * 256, Vt + th * T_ * 64,
                                                     Sinit, y16);
        glu_k<<<dim3(L_ / 64, B_), 256, 0, stream>>>(W16 + (size_t)i * 2 * H_ * H_, y16,
                                                     out_b + i * 2 * H_, ln_w + th, ln_b + th, z16);
    }
    decoder_k<<<B_ * 64, 256, 0, stream>>>(z16, dec_w, dec_b, outp);
}

// Round 5
// 550.611 us; speedup vs baseline: 5.0527x; 1.1099x over previous
//
#include <hip/hip_runtime.h>
#include <hip/hip_fp16.h>

#define B_   16
#define L_   4096
#define DIN  64
#define H_   256
#define N_   32
#define NL_  4
#define DOUT 10
#define CH_  32
#define T_   128

typedef _Float16 half8 __attribute__((ext_vector_type(8)));
typedef _Float16 half4 __attribute__((ext_vector_type(4)));
typedef float f32x4 __attribute__((ext_vector_type(4)));

__device__ __forceinline__ float gelu_f(float v) {
    float t3  = v * v * v;
    float arg = 0.7978845608028654f * fmaf(0.044715f, t3, v);
    float e   = __expf(2.f * arg);
    float th  = 1.f - 2.f / (e + 1.f);
    return 0.5f * v * (1.f + th);
}

// ---------------- table generation: per (layer,h) block ----------------
__global__ __launch_bounds__(256) void gen_k(
    const float* __restrict__ log_dt, const float* __restrict__ log_A_real,
    const float* __restrict__ A_imag, const float* __restrict__ C_re, const float* __restrict__ C_im,
    const float* __restrict__ Dp,
    _Float16* __restrict__ Wv, _Float16* __restrict__ Vt, _Float16* __restrict__ G,
    float* __restrict__ wtr, float* __restrict__ wti)
{
    __shared__ float sxr[N_], sxi[N_], scr[N_], sci[N_], skd[T_];
    int ih = blockIdx.x;
    int t  = threadIdx.x;
    if (t < N_) {
        int n = t;
        float dt  = expf(log_dt[ih]);
        float Are = -expf(log_A_real[ih * N_ + n]);
        float Aim = A_imag[ih * N_ + n];
        float xr = dt * Are, xi = dt * Aim;
        float ex = expf(xr), cy = cosf(xi), sy = sinf(xi);
        float sh = sinf(0.5f * xi);
        float em_re = expm1f(xr) * cy - 2.f * sh * sh;
        float em_im = ex * sy;
        float inv = 1.f / (Are * Are + Aim * Aim);
        float qr = (em_re * Are + em_im * Aim) * inv;
        float qi = (em_im * Are - em_re * Aim) * inv;
        float crv = C_re[ih * N_ + n], civ = C_im[ih * N_ + n];
        sxr[n] = xr; sxi[n] = xi;
        scr[n] = 2.f * (crv * qr - civ * qi);
        sci[n] = 2.f * (crv * qi + civ * qr);
        float txr = 128.f * xr, txi = 128.f * xi;
        float exT = expf(txr);
        wtr[ih * N_ + n] = exT * cosf(txi);
        wti[ih * N_ + n] = exT * sinf(txi);
    }
    __syncthreads();
    if (t <= T_) {
        int d = t;
        float fd = (float)d;
        float kd = 0.f;
        for (int n = 0; n < N_; n++) {
            float ar = expf(fd * sxr[n]);
            float ang = fd * sxi[n];
            float wdr = ar * cosf(ang), wdi = ar * sinf(ang);
            if (d < T_) {
                kd = fmaf(scr[n], wdr, kd);
                kd = fmaf(-sci[n], wdi, kd);
                Wv[((size_t)ih * 64 + 2 * n) * T_ + (127 - d)]     = (_Float16)wdr;
                Wv[((size_t)ih * 64 + 2 * n + 1) * T_ + (127 - d)] = (_Float16)wdi;
            }
            if (d >= 1) {
                float vr = scr[n] * wdr - sci[n] * wdi;
                float vi = scr[n] * wdi + sci[n] * wdr;
                Vt[((size_t)ih * T_ + (d - 1)) * 64 + 2 * n]     = (_Float16)vr;
                Vt[((size_t)ih * T_ + (d - 1)) * 64 + 2 * n + 1] = (_Float16)(-vi);
            }
        }
        if (d < T_) skd[d] = kd;
    }
    __syncthreads();
    if (t < T_) {
        float v = skd[127 - t];
        if (t == 127) v += Dp[ih];
        G[(size_t)ih * 256 + t]       = (_Float16)v;
        G[(size_t)ih * 256 + 128 + t] = (_Float16)0.f;
    }
}

__global__ __launch_bounds__(256) void wconv_k(const float* __restrict__ w, _Float16* __restrict__ w16)
{
    int idx = blockIdx.x * 256 + threadIdx.x;
    w16[idx] = (_Float16)w[idx];
}

// decoder weight prep: 16x256 f16, rows >= DOUT zeroed
__global__ __launch_bounds__(256) void dprep_k(const float* __restrict__ dw, _Float16* __restrict__ dwp)
{
    int t = threadIdx.x;
#pragma unroll
    for (int j = 0; j < 16; j++) {
        int idx = j * 256 + t;
        dwp[idx] = (idx < DOUT * H_) ? (_Float16)dw[idx] : (_Float16)0.f;
    }
}

// ---------------- encoder: MFMA GEMM, M=256(h) x N=128(l) x K=64 ----------------
__global__ __launch_bounds__(256) void encoder_k(
    const float* __restrict__ x, const float* __restrict__ ew,
    const float* __restrict__ eb, _Float16* __restrict__ z16)
{
    __shared__ _Float16 smem[35840];      // 71680 B: xs[128][72]+ews[256][72] | ot[256][136]
    _Float16* xs  = smem;                 // [128][72]
    _Float16* ews = smem + 128 * 72;      // [256][72]
    _Float16* ot  = smem;                 // [256][136]
    int b  = blockIdx.y;
    int l0 = blockIdx.x << 7;
    int t  = threadIdx.x;
#pragma unroll
    for (int j = 0; j < 8; j++) {
        int idx = j * 256 + t;
        int l = idx >> 4, i4 = (idx & 15) * 4;
        float4 v = *(const float4*)(x + ((size_t)(b * L_ + l0 + l)) * DIN + i4);
        _Float16 c[4] = {(_Float16)v.x, (_Float16)v.y, (_Float16)v.z, (_Float16)v.w};
        *(uint2*)&xs[l * 72 + i4] = *(uint2*)c;
    }
#pragma unroll
    for (int j = 0; j < 16; j++) {
        int idx = j * 256 + t;
        int h = idx >> 4, i4 = (idx & 15) * 4;
        float4 v = *(const float4*)(ew + h * 64 + i4);
        _Float16 c[4] = {(_Float16)v.x, (_Float16)v.y, (_Float16)v.z, (_Float16)v.w};
        *(uint2*)&ews[h * 72 + i4] = *(uint2*)c;
    }
    __syncthreads();
    int lane = t & 63, wid = t >> 6;
    int l15 = lane & 15, quad = lane >> 4;
    f32x4 acc[4][8];
#pragma unroll
    for (int mt = 0; mt < 4; mt++)
#pragma unroll
        for (int nt = 0; nt < 8; nt++) acc[mt][nt] = (f32x4){0.f,0.f,0.f,0.f};
#pragma unroll
    for (int ks = 0; ks < 2; ks++) {
        int kk = ks * 32 + quad * 8;
        half8 a[4], bb[8];
#pragma unroll
        for (int mt = 0; mt < 4; mt++)
            a[mt] = *(const half8*)&ews[(wid * 64 + mt * 16 + l15) * 72 + kk];
#pragma unroll
        for (int nt = 0; nt < 8; nt++)
            bb[nt] = *(const half8*)&xs[(nt * 16 + l15) * 72 + kk];
#pragma unroll
        for (int mt = 0; mt < 4; mt++)
#pragma unroll
            for (int nt = 0; nt < 8; nt++)
                acc[mt][nt] = __builtin_amdgcn_mfma_f32_16x16x32_f16(a[mt], bb[nt], acc[mt][nt], 0, 0, 0);
    }
    __syncthreads();                      // staging dead; reuse as ot
#pragma unroll
    for (int mt = 0; mt < 4; mt++) {
        int hb = wid * 64 + mt * 16 + quad * 4;
        float b0 = eb[hb], b1 = eb[hb + 1], b2 = eb[hb + 2], b3 = eb[hb + 3];
#pragma unroll
        for (int nt = 0; nt < 8; nt++) {
            int l = nt * 16 + l15;
            ot[(hb + 0) * 136 + l] = (_Float16)(acc[mt][nt][0] + b0);
            ot[(hb + 1) * 136 + l] = (_Float16)(acc[mt][nt][1] + b1);
            ot[(hb + 2) * 136 + l] = (_Float16)(acc[mt][nt][2] + b2);
            ot[(hb + 3) * 136 + l] = (_Float16)(acc[mt][nt][3] + b3);
        }
    }
    __syncthreads();
#pragma unroll
    for (int p = 0; p < 16; p++) {
        int row = p * 16 + (t >> 4), seg = t & 15;
        uint4 v = *(uint4*)&ot[row * 136 + seg * 8];
        *(uint4*)(z16 + ((size_t)(b * H_ + row)) * L_ + l0 + seg * 8) = v;
    }
}

// ---------------- finals + fused chunk-prefix ----------------
__global__ __launch_bounds__(256) void finals_k(
    const _Float16* __restrict__ z16, const _Float16* __restrict__ Wv,
    const float* __restrict__ wtr, const float* __restrict__ wti,
    _Float16* __restrict__ Sinit)
{
    __shared__ _Float16 zb[CH_][136];
    __shared__ float Fs[CH_][68];
    int h = blockIdx.x, b = blockIdx.y;
    int t = threadIdx.x;
    const uint4* src = (const uint4*)(z16 + ((size_t)(b * H_ + h)) * L_);
#pragma unroll
    for (int j = 0; j < 2; j++) {
        uint4 v = src[t * 2 + j];
        int e0 = (t * 2 + j) * 8;
        *(uint4*)&zb[e0 >> 7][e0 & 127] = v;
    }
    __syncthreads();
    int lane = t & 63, w = t >> 6;
    int l15 = lane & 15, quad = lane >> 4;
    f32x4 acc[2];
    acc[0] = (f32x4){0.f,0.f,0.f,0.f};
    acc[1] = (f32x4){0.f,0.f,0.f,0.f};
    const _Float16* wvb = Wv + ((size_t)h * 64 + w * 16 + l15) * T_;
#pragma unroll
    for (int ks = 0; ks < 4; ks++) {
        int kk = ks * 32 + quad * 8;
        half8 a  = *(const half8*)(wvb + kk);
        half8 b0 = *(const half8*)&zb[l15][kk];
        half8 b1 = *(const half8*)&zb[16 + l15][kk];
        acc[0] = __builtin_amdgcn_mfma_f32_16x16x32_f16(a, b0, acc[0], 0, 0, 0);
        acc[1] = __builtin_amdgcn_mfma_f32_16x16x32_f16(a, b1, acc[1], 0, 0, 0);
    }
#pragma unroll
    for (int nt = 0; nt < 2; nt++) {
        int c = nt * 16 + l15;
        *(f32x4*)&Fs[c][w * 16 + quad * 4] = acc[nt];
    }
    __syncthreads();
    if (t < N_) {
        int n = t;
        float wr = wtr[h * N_ + n], wi = wti[h * N_ + n];
        float cr = 0.f, ci = 0.f;
        _Float16* sb = Sinit + ((size_t)(b * H_ + h)) * (CH_ * 64) + 2 * n;
        for (int c = 0; c < CH_; c++) {
            float2 f2 = *(const float2*)&Fs[c][2 * n];
            union { unsigned u; _Float16 hf[2]; } p;
            p.hf[0] = (_Float16)cr; p.hf[1] = (_Float16)ci;
            *(unsigned*)(sb + (size_t)c * 64) = p.u;
            float nr = fmaf(wr, cr, f2.x);
            nr = fmaf(-wi, ci, nr);
            float ni = fmaf(wi, cr, f2.y);
            ni = fmaf(wr, ci, ni);
            cr = nr; ci = ni;
        }
    }
}

// ---------------- conv GEMM: y = gelu( Km@Z^T + Vt@Sinit^T ) -> y16 ----------------
__global__ __launch_bounds__(256) void conv_k(
    const _Float16* __restrict__ z16, const _Float16* __restrict__ G,
    const _Float16* __restrict__ Vt, const _Float16* __restrict__ Sinit,
    _Float16* __restrict__ y16)
{
    __shared__ _Float16 zT[128][136];
    __shared__ _Float16 Ff[128][72];
    __shared__ _Float16 Gs[256];
    int h = blockIdx.x, rb = blockIdx.y;
    int t = threadIdx.x;
    int b0 = rb * 4;
#pragma unroll
    for (int q = 0; q < 8; q++) {
        int idx = q * 256 + t;
        int brow = idx >> 9;
        int e = (idx & 511) * 8;
        uint4 v = *(const uint4*)(z16 + ((size_t)((b0 + brow) * H_ + h)) * L_ + e);
        int c = e >> 7, jj = e & 127;
        *(uint4*)&zT[brow * 32 + c][jj] = v;
    }
#pragma unroll
    for (int q = 0; q < 4; q++) {
        int idx = q * 256 + t;
        int e0 = idx * 8;
        int brow = e0 >> 11;
        int off = e0 & 2047;
        uint4 v = *(const uint4*)(Sinit + ((size_t)((b0 + brow) * H_ + h)) * (CH_ * 64) + off);
        int r = brow * 32 + (off >> 6), k = off & 63;
        *(uint4*)&Ff[r][k] = v;
    }
    Gs[t] = G[(size_t)h * 256 + t];
    __syncthreads();
    int lane = t & 63, w = t >> 6;
    int l15 = lane & 15, quad = lane >> 4;
    f32x4 acc[2][8];
#pragma unroll
    for (int mt = 0; mt < 2; mt++)
#pragma unroll
        for (int nt = 0; nt < 8; nt++) acc[mt][nt] = (f32x4){0.f,0.f,0.f,0.f};
#pragma unroll
    for (int ks = 0; ks < 4; ks++) {
        int kk = ks * 32 + quad * 8;
        int base0 = 127 - (w * 32 + l15) + kk;
        int base1 = base0 - 16;
        half8 a0, a1;
#pragma unroll
        for (int j = 0; j < 8; j++) { a0[j] = Gs[base0 + j]; a1[j] = Gs[base1 + j]; }
#pragma unroll
        for (int nt = 0; nt < 8; nt++) {
            half8 bf = *(const half8*)&zT[nt * 16 + l15][kk];
            acc[0][nt] = __builtin_amdgcn_mfma_f32_16x16x32_f16(a0, bf, acc[0][nt], 0, 0, 0);
            acc[1][nt] = __builtin_amdgcn_mfma_f32_16x16x32_f16(a1, bf, acc[1][nt], 0, 0, 0);
        }
    }
    const _Float16* vb = Vt + (size_t)h * T_ * 64;
#pragma unroll
    for (int ks = 0; ks < 2; ks++) {
        int kk = ks * 32 + quad * 8;
        half8 a0 = *(const half8*)(vb + ((size_t)(w * 32 + l15)) * 64 + kk);
        half8 a1 = *(const half8*)(vb + ((size_t)(w * 32 + 16 + l15)) * 64 + kk);
#pragma unroll
        for (int nt = 0; nt < 8; nt++) {
            half8 bf = *(const half8*)&Ff[nt * 16 + l15][kk];
            acc[0][nt] = __builtin_amdgcn_mfma_f32_16x16x32_f16(a0, bf, acc[0][nt], 0, 0, 0);
            acc[1][nt] = __builtin_amdgcn_mfma_f32_16x16x32_f16(a1, bf, acc[1][nt], 0, 0, 0);
        }
    }
    __syncthreads();
#pragma unroll
    for (int mt = 0; mt < 2; mt++)
#pragma unroll
        for (int nt = 0; nt < 8; nt++) {
            int r = nt * 16 + l15;
            int tt0 = w * 32 + mt * 16 + quad * 4;
            _Float16 o[4];
#pragma unroll
            for (int rr = 0; rr < 4; rr++) o[rr] = (_Float16)gelu_f(acc[mt][nt][rr]);
            *(uint2*)&zT[r][tt0] = *(uint2*)o;
        }
    __syncthreads();
#pragma unroll
    for (int q = 0; q < 8; q++) {
        int idx = q * 256 + t;
        int brow = idx >> 9;
        int e = (idx & 511) * 8;
        int c = e >> 7, jj = e & 127;
        uint4 v = *(uint4*)&zT[brow * 32 + c][jj];
        *(uint4*)(y16 + ((size_t)((b0 + brow) * H_ + h)) * L_ + e) = v;
    }
}

// ---------------- GLU GEMM (M=512, N=64) + residual + LN, f16 in/out ----------------
__global__ __launch_bounds__(256, 2) void glu_k(
    const _Float16* __restrict__ W, const _Float16* __restrict__ y16,
    const float* __restrict__ outb, const float* __restrict__ lnw,
    const float* __restrict__ lnb, _Float16* __restrict__ z16)
{
    __shared__ float u_s[256 * 66];
    __shared__ float red[2][4][64];
    __shared__ float mus[64], rss[64];
    _Float16* yT = (_Float16*)u_s;
    int b  = blockIdx.y;
    int l0 = blockIdx.x << 6;
    int t  = threadIdx.x;
    int lane = t & 63, wid = t >> 6;
    int l15 = lane & 15, quad = lane >> 4;
    {
        const uint4* src = (const uint4*)(y16 + ((size_t)(b * H_ + t)) * L_ + l0);
        uint4 v[8];
#pragma unroll
        for (int j = 0; j < 8; j++) v[j] = src[j];
        const _Float16* hv = (const _Float16*)v;
#pragma unroll
        for (int j = 0; j < 64; j++) yT[j * 264 + t] = hv[j];
    }
    __syncthreads();
    f32x4 acc[8][4];
#pragma unroll
    for (int mt = 0; mt < 8; mt++)
#pragma unroll
        for (int nt = 0; nt < 4; nt++) acc[mt][nt] = (f32x4){0.f,0.f,0.f,0.f};
#pragma unroll
    for (int ks = 0; ks < 8; ks++) {
        int kk = ks * 32 + quad * 8;
        half8 bf[4];
#pragma unroll
        for (int nt = 0; nt < 4; nt++) bf[nt] = *(const half8*)&yT[(nt * 16 + l15) * 264 + kk];
#pragma unroll
        for (int mt = 0; mt < 8; mt++) {
            int row = (mt >> 2) * 256 + wid * 64 + (mt & 3) * 16 + l15;
            half8 a = *(const half8*)(W + (size_t)row * H_ + kk);
#pragma unroll
            for (int nt = 0; nt < 4; nt++)
                acc[mt][nt] = __builtin_amdgcn_mfma_f32_16x16x32_f16(a, bf[nt], acc[mt][nt], 0, 0, 0);
        }
    }
    __syncthreads();
#pragma unroll
    for (int mt = 0; mt < 4; mt++) {
        int chb = wid * 64 + mt * 16 + quad * 4;
        float4 ob1 = *(const float4*)(outb + chb);
        float4 ob2 = *(const float4*)(outb + 256 + chb);
        const float* o1 = (const float*)&ob1;
        const float* o2 = (const float*)&ob2;
#pragma unroll
        for (int nt = 0; nt < 4; nt++) {
            int l = nt * 16 + l15;
#pragma unroll
            for (int r = 0; r < 4; r++) {
                float g1 = acc[mt][nt][r] + o1[r];
                float g2 = acc[mt + 4][nt][r] + o2[r];
                float sg = 1.f / (1.f + __expf(-g2));
                u_s[(chb + r) * 66 + l] = g1 * sg;
            }
        }
    }
    __syncthreads();
    int lr = t & 63, grp = t >> 6;
    float s1 = 0.f, s2 = 0.f;
    for (int j = 0; j < 64; j++) {
        int ch = grp * 64 + j;
        float uu = u_s[ch * 66 + lr] + (float)z16[((size_t)(b * H_ + ch)) * L_ + l0 + lr];
        u_s[ch * 66 + lr] = uu;
        s1 += uu; s2 = fmaf(uu, uu, s2);
    }
    red[0][grp][lr] = s1; red[1][grp][lr] = s2;
    __syncthreads();
    if (t < 64) {
        float a = red[0][0][t] + red[0][1][t] + red[0][2][t] + red[0][3][t];
        float q = red[1][0][t] + red[1][1][t] + red[1][2][t] + red[1][3][t];
        float mu  = a * (1.f / 256.f);
        float var = q * (1.f / 256.f) - mu * mu;
        mus[t] = mu; rss[t] = rsqrtf(var + 1e-5f);
    }
    __syncthreads();
    int lg = (t & 15) * 4, ch0 = t >> 4;
    float mu4[4], rs4[4];
#pragma unroll
    for (int i = 0; i < 4; i++) { mu4[i] = mus[lg + i]; rs4[i] = rss[lg + i]; }
#pragma unroll
    for (int j = 0; j < 16; j++) {
        int ch = ch0 + 16 * j;
        float wv = lnw[ch], bv = lnb[ch];
        _Float16 o4[4];
#pragma unroll
        for (int i = 0; i < 4; i++) {
            float vv = (u_s[ch * 66 + lg + i] - mu4[i]) * rs4[i] * wv + bv;
            o4[i] = (_Float16)vv;
        }
        *(uint2*)(z16 + ((size_t)(b * H_ + ch)) * L_ + l0 + lg) = *(uint2*)o4;
    }
}

// ---------------- decoder: MFMA, m=o(16 padded), n=l, k=h=256 ----------------
__global__ __launch_bounds__(256) void decoder_k(
    const _Float16* __restrict__ z16, const _Float16* __restrict__ dwp,
    const float* __restrict__ db, float* __restrict__ out)
{
    __shared__ _Float16 zT[128][268];     // [l][h], 68.6 KB; pitch 268 -> b64 frag reads conflict-free
    int b  = blockIdx.y;
    int l0 = blockIdx.x << 7;
    int t  = threadIdx.x;
    // stage transpose: coalesced uint reads (lanes consecutive in l)
#pragma unroll 8
    for (int j = 0; j < 64; j++) {
        int idx = j * 256 + t;
        int h = idx >> 6, lp = idx & 63;
        unsigned v = *(const unsigned*)(z16 + ((size_t)(b * H_ + h)) * L_ + l0 + lp * 2);
        union { unsigned u; _Float16 f[2]; } c; c.u = v;
        zT[lp * 2][h]     = c.f[0];
        zT[lp * 2 + 1][h] = c.f[1];
    }
    __syncthreads();
    int lane = t & 63, wid = t >> 6;
    int l15 = lane & 15, quad = lane >> 4;
    f32x4 acc[2];
    acc[0] = (f32x4){0.f,0.f,0.f,0.f};
    acc[1] = (f32x4){0.f,0.f,0.f,0.f};
#pragma unroll
    for (int ks = 0; ks < 8; ks++) {
        int kk = ks * 32 + quad * 8;
        half8 a = *(const half8*)(dwp + l15 * 256 + kk);
#pragma unroll
        for (int nt = 0; nt < 2; nt++) {
            int l = (wid * 2 + nt) * 16 + l15;
            half4 lo = *(const half4*)&zT[l][kk];
            half4 hi = *(const half4*)&zT[l][kk + 4];
            half8 bf;
#pragma unroll
            for (int j = 0; j < 4; j++) { bf[j] = lo[j]; bf[j + 4] = hi[j]; }
            acc[nt] = __builtin_amdgcn_mfma_f32_16x16x32_f16(a, bf, acc[nt], 0, 0, 0);
        }
    }
    int o0 = quad * 4;
#pragma unroll
    for (int nt = 0; nt < 2; nt++) {
        int l = (wid * 2 + nt) * 16 + l15;
        float* op = out + ((size_t)(b * L_ + l0 + l)) * DOUT;
#pragma unroll
        for (int r = 0; r < 4; r++) {
            int o = o0 + r;
            if (o < DOUT) op[o] = acc[nt][r] + db[o];
        }
    }
}

extern "C" void kernel_launch(void* const* d_in, const int* in_sizes, int n_in,
                              void* d_out, int out_size, void* d_ws, size_t ws_size,
                              hipStream_t stream)
{
    (void)in_sizes; (void)n_in; (void)out_size; (void)ws_size;
    const float* x          = (const float*)d_in[0];
    const float* enc_w      = (const float*)d_in[1];
    const float* enc_b      = (const float*)d_in[2];
    const float* log_dt     = (const float*)d_in[3];
    const float* log_A_real = (const float*)d_in[4];
    const float* A_imag     = (const float*)d_in[5];
    const float* C_re       = (const float*)d_in[6];
    const float* C_im       = (const float*)d_in[7];
    const float* Dp         = (const float*)d_in[8];
    const float* out_w      = (const float*)d_in[9];
    const float* out_b      = (const float*)d_in[10];
    const float* ln_w       = (const float*)d_in[11];
    const float* ln_b       = (const float*)d_in[12];
    const float* dec_w      = (const float*)d_in[13];
    const float* dec_b      = (const float*)d_in[14];
    float* outp = (float*)d_out;

    char* ws = (char*)d_ws;
    _Float16* z16 = (_Float16*)ws;   ws += (size_t)B_ * H_ * L_ * 2;
    _Float16* y16 = (_Float16*)ws;   ws += (size_t)B_ * H_ * L_ * 2;
    _Float16* Sinit = (_Float16*)ws; ws += (size_t)B_ * H_ * CH_ * 64 * 2;
    _Float16* Wv = (_Float16*)ws;    ws += (size_t)NL_ * H_ * 64 * T_ * 2;
    _Float16* Vt = (_Float16*)ws;    ws += (size_t)NL_ * H_ * T_ * 64 * 2;
    _Float16* G  = (_Float16*)ws;    ws += (size_t)NL_ * H_ * 256 * 2;
    size_t tb = (size_t)NL_ * H_ * N_;
    float* wtr = (float*)ws; ws += tb * 4;
    float* wti = (float*)ws; ws += tb * 4;
    _Float16* W16 = (_Float16*)ws; ws += (size_t)NL_ * 2 * H_ * H_ * 2;
    _Float16* dwp = (_Float16*)ws; ws += (size_t)16 * H_ * 2;

    gen_k<<<NL_ * H_, 256, 0, stream>>>(log_dt, log_A_real, A_imag, C_re, C_im, Dp,
                                        Wv, Vt, G, wtr, wti);
    wconv_k<<<(NL_ * 2 * H_ * H_) / 256, 256, 0, stream>>>(out_w, W16);
    dprep_k<<<1, 256, 0, stream>>>(dec_w, dwp);
    encoder_k<<<dim3(L_ / 128, B_), 256, 0, stream>>>(x, enc_w, enc_b, z16);
    for (int i = 0; i < NL_; i++) {
        size_t th = (size_t)i * H_;
        finals_k<<<dim3(H_, B_), 256, 0, stream>>>(z16, Wv + th * 64 * T_,
                                                   wtr + th * N_, wti + th * N_, Sinit);
        conv_k<<<dim3(H_, B_ / 4), 256, 0, stream>>>(z16, G + th * 256, Vt + th * T_ * 64,
                                                     Sinit, y16);
        glu_k<<<dim3(L_ / 64, B_), 256, 0, stream>>>(W16 + (size_t)i * 2 * H_ * H_, y16,
                                                     out_b + i * 2 * H_, ln_w + th, ln_b + th, z16);
    }
    decoder_k<<<dim3(L_ / 128, B_), 256, 0, stream>>>(z16, dwp, dec_b, outp);
}